// Round 1
// baseline (6170.352 us; speedup 1.0000x reference)
//
#include <hip/hip_runtime.h>
#include <math.h>

// Res_Slim_ViT_Adaptive — full fp32 implementation.
// Shapes: P=16 D=1024 NH=16 HD=64 MAG=4 B=2 V=4 H=256 W=512 L=512 KEEP=128 DEPTH=6

#define UNIT 1048576L   // 1M floats

__device__ __forceinline__ float gelu_f(float v){
  return 0.5f*v*(1.0f + erff(v*0.70710678118654752440f));
}

// ---------------- generic batched fp32 GEMM: C = act(A@W + bias + res) ----------------
// 64x64 tile, BK=16, 256 threads, 4x4 per thread. M,N mult of 64 (M=128 ok), K mult of 16.
__global__ __launch_bounds__(256)
void gemm_f32(const float* __restrict__ A, const float* __restrict__ W,
              const float* __restrict__ bias, const float* __restrict__ res,
              float* __restrict__ C,
              int M, int N, int K, int lda, int ldw, int ldc,
              long sA, long sW, long sBias, long sRes, long sC,
              int wmod, int act)
{
  int bz = blockIdx.z;
  A += (long)bz * sA;
  C += (long)bz * sC;
  int wb = bz % wmod;
  W += (long)wb * sW;
  const float* bptr = bias ? bias + (long)wb * sBias : nullptr;
  const float* rptr = res  ? res  + (long)bz * sRes : nullptr;

  __shared__ float As[16][66];   // [k][m], padded
  __shared__ float Ws[16][64];   // [k][n]
  int t  = threadIdx.x;
  int tx = t & 15, ty = t >> 4;
  int row0 = blockIdx.y * 64, col0 = blockIdx.x * 64;
  float acc[4][4] = {{0.f}};

  int am = t >> 2, ak = (t & 3) << 2;       // A tile: 64 rows x 16 k, 4 floats/thread
  int wk = t >> 4, wn = (t & 15) << 2;      // W tile: 16 k x 64 cols
  const float* aP = A + (long)(row0 + am) * lda + ak;
  const float* wP = W + (long)wk * ldw + col0 + wn;

  for (int k0 = 0; k0 < K; k0 += 16){
    float4 a4 = *(const float4*)(aP + k0);
    float4 w4 = *(const float4*)(wP + (long)k0 * ldw);
    As[ak+0][am] = a4.x; As[ak+1][am] = a4.y; As[ak+2][am] = a4.z; As[ak+3][am] = a4.w;
    *(float4*)&Ws[wk][wn] = w4;
    __syncthreads();
    #pragma unroll
    for (int kk = 0; kk < 16; ++kk){
      float av[4], bv[4];
      #pragma unroll
      for (int i = 0; i < 4; ++i) av[i] = As[kk][ty*4 + i];
      #pragma unroll
      for (int j = 0; j < 4; ++j) bv[j] = Ws[kk][tx*4 + j];
      #pragma unroll
      for (int i = 0; i < 4; ++i)
        #pragma unroll
        for (int j = 0; j < 4; ++j) acc[i][j] += av[i] * bv[j];
    }
    __syncthreads();
  }

  #pragma unroll
  for (int i = 0; i < 4; ++i){
    int r = row0 + ty*4 + i;
    #pragma unroll
    for (int j = 0; j < 4; ++j){
      int c = col0 + tx*4 + j;
      float v = acc[i][j];
      if (bptr) v += bptr[c];
      if (rptr) v += rptr[(long)r * ldc + c];
      if (act == 1) v = gelu_f(v);
      C[(long)r * ldc + c] = v;
    }
  }
}

// ---------------- LayerNorm over D=1024, one row per block (256 thr, 4 floats/thr) -----
__global__ __launch_bounds__(256)
void ln_kernel(const float* __restrict__ x, const float* __restrict__ g,
               const float* __restrict__ b, float* __restrict__ y)
{
  long r = blockIdx.x;
  int t = threadIdx.x;
  float4 v = ((const float4*)(x + r*1024))[t];
  float s  = v.x + v.y + v.z + v.w;
  float ss = v.x*v.x + v.y*v.y + v.z*v.z + v.w*v.w;
  #pragma unroll
  for (int o = 32; o; o >>= 1){ s += __shfl_xor(s, o); ss += __shfl_xor(ss, o); }
  __shared__ float sa[4], sb[4];
  int w = t >> 6, lane = t & 63;
  if (!lane){ sa[w] = s; sb[w] = ss; }
  __syncthreads();
  s  = sa[0] + sa[1] + sa[2] + sa[3];
  ss = sb[0] + sb[1] + sb[2] + sb[3];
  float mean = s * (1.0f/1024.0f);
  float var  = ss * (1.0f/1024.0f) - mean*mean;
  float rstd = rsqrtf(var + 1e-5f);
  float4 gv = ((const float4*)g)[t];
  float4 bv = ((const float4*)b)[t];
  float4 o;
  o.x = (v.x-mean)*rstd*gv.x + bv.x;
  o.y = (v.y-mean)*rstd*gv.y + bv.y;
  o.z = (v.z-mean)*rstd*gv.z + bv.z;
  o.w = (v.w-mean)*rstd*gv.w + bv.w;
  ((float4*)(y + r*1024))[t] = o;
}

// ---------------- patch extraction: x (B,V,256,512) -> xp (B,V,L=512,256) --------------
__global__ void xp_extract(const float* __restrict__ x, float* __restrict__ xp)
{
  int idx = blockIdx.x * 256 + threadIdx.x;          // 262144 float4s
  int e4 = idx & 63;                                 // e = e4*4
  int l  = (idx >> 6) & 511;
  int z  = idx >> 15;                                // b*4+v
  int e  = e4 << 2;
  int py = e >> 4, px0 = e & 15;
  int hy = l >> 5, wx = l & 31;
  float4 v = *(const float4*)&x[((long)z*256 + hy*16 + py)*512 + wx*16 + px0];
  ((float4*)xp)[idx] = v;
}

__global__ void pb2_combine(const float* __restrict__ pb, const float* __restrict__ ve,
                            float* __restrict__ out)
{
  int i = blockIdx.x * 256 + threadIdx.x;            // 4096
  out[i] = pb[i] + ve[i];
}

// q = var_query @ agg_wq  (1x1024 @ 1024x1024)
__global__ void qproj(const float* __restrict__ vq, const float* __restrict__ wq,
                      float* __restrict__ q)
{
  int n = blockIdx.x * 64 + threadIdx.x;             // 1024
  float s = 0.f;
  for (int k = 0; k < 1024; ++k) s += vq[k] * wq[(long)k*1024 + n];
  q[n] = s;
}

// aggregate_variables attention: softmax over V=4 per (b,l,h); kb/vb layout (B,V,L,D)
__global__ __launch_bounds__(64)
void agg_attn(const float* __restrict__ kb, const float* __restrict__ vb,
              const float* __restrict__ q, float* __restrict__ out)
{
  int l = blockIdx.x, h = blockIdx.y, b = blockIdx.z, t = threadIdx.x;
  float qd = q[h*64 + t];
  long off[4];
  float s[4];
  #pragma unroll
  for (int v = 0; v < 4; ++v){
    off[v] = ((((long)b*4 + v)*512 + l)*1024) + h*64 + t;
    float p = qd * kb[off[v]];
    #pragma unroll
    for (int o = 32; o; o >>= 1) p += __shfl_xor(p, o);
    s[v] = p * 0.125f;
  }
  float m = fmaxf(fmaxf(s[0], s[1]), fmaxf(s[2], s[3]));
  float e0 = __expf(s[0]-m), e1 = __expf(s[1]-m), e2 = __expf(s[2]-m), e3 = __expf(s[3]-m);
  float inv = 1.0f / (e0 + e1 + e2 + e3);
  float o = e0*vb[off[0]] + e1*vb[off[1]] + e2*vb[off[2]] + e3*vb[off[3]];
  out[(((long)b*512 + l)*1024) + h*64 + t] = o * inv;
}

// transformer self-attention: one q-row per block (1 wave). qkv (B,N,3072)
__global__ __launch_bounds__(64)
void attn_kernel(const float* __restrict__ qkv, float* __restrict__ out, int N)
{
  int i = blockIdx.x, h = blockIdx.y, b = blockIdx.z, t = threadIdx.x;
  const float* base = qkv + (long)b * N * 3072;
  __shared__ float qs[64];
  __shared__ float sc[512];
  qs[t] = base[(long)i*3072 + h*64 + t];
  __syncthreads();
  for (int j = t; j < N; j += 64){
    const float* kr = base + (long)j*3072 + 1024 + h*64;
    float s = 0.f;
    #pragma unroll
    for (int d = 0; d < 64; ++d) s += qs[d] * kr[d];
    sc[j] = s * 0.125f;
  }
  __syncthreads();
  float m = -1e30f;
  for (int j = t; j < N; j += 64) m = fmaxf(m, sc[j]);
  #pragma unroll
  for (int o = 32; o; o >>= 1) m = fmaxf(m, __shfl_xor(m, o));
  float ssum = 0.f;
  for (int j = t; j < N; j += 64){ float e = __expf(sc[j]-m); sc[j] = e; ssum += e; }
  #pragma unroll
  for (int o = 32; o; o >>= 1) ssum += __shfl_xor(ssum, o);
  float inv = 1.0f / ssum;
  __syncthreads();
  float acc = 0.f;
  for (int j = 0; j < N; ++j) acc += sc[j] * base[(long)j*3072 + 2048 + h*64 + t];
  out[((long)b*N + i)*1024 + h*64 + t] = acc * inv;
}

// gather / scatter 128 hard tokens per batch
__global__ __launch_bounds__(256)
void gather_rows(const float* __restrict__ src, const int* __restrict__ idx,
                 float* __restrict__ dst)
{
  int r = blockIdx.x;            // B*128
  int b = r >> 7, i = r & 127;
  int s = idx[b*128 + i];
  ((float4*)(dst + (long)r*1024))[threadIdx.x] =
      ((const float4*)(src + ((long)b*512 + s)*1024))[threadIdx.x];
}
__global__ __launch_bounds__(256)
void scatter_rows(const float* __restrict__ src, const int* __restrict__ idx,
                  float* __restrict__ dst)
{
  int r = blockIdx.x;
  int b = r >> 7, i = r & 127;
  int s = idx[b*128 + i];
  ((float4*)(dst + ((long)b*512 + s)*1024))[threadIdx.x] =
      ((const float4*)(src + (long)r*1024))[threadIdx.x];
}

// conv1: x (B,4,256,512) -> gelu(conv3x3) -> (B,64,256,512)
__global__ void conv1_kernel(const float* __restrict__ x, const float* __restrict__ w,
                             const float* __restrict__ bi, float* __restrict__ out)
{
  long idx = (long)blockIdx.x*256 + threadIdx.x;   // 16,777,216
  int px = idx & 511, py = (idx >> 9) & 255, co = (idx >> 17) & 63, bb = (int)(idx >> 23);
  float s = bi[co];
  #pragma unroll
  for (int ci = 0; ci < 4; ++ci){
    const float* xc = x + ((long)(bb*4 + ci)*256)*512;
    const float* wc = w + (co*4 + ci)*9;
    #pragma unroll
    for (int ky = 0; ky < 3; ++ky){
      int yy = py + ky - 1; if ((unsigned)yy >= 256u) continue;
      #pragma unroll
      for (int kx = 0; kx < 3; ++kx){
        int xx = px + kx - 1; if ((unsigned)xx >= 512u) continue;
        s += xc[yy*512 + xx] * wc[ky*3 + kx];
      }
    }
  }
  out[idx] = gelu_f(s);
}

// conv2 fused with pixel_shuffle(r=4): r1 (B,64,256,512) -> (B,1,1024,2048)
__global__ void conv2_kernel(const float* __restrict__ r1, const float* __restrict__ w,
                             const float* __restrict__ bi, float* __restrict__ out)
{
  long idx = (long)blockIdx.x*256 + threadIdx.x;   // 4,194,304
  int X = idx & 2047, Y = (idx >> 11) & 1023, bb = (int)(idx >> 21);
  float s = bi[0];
  #pragma unroll
  for (int ci = 0; ci < 4; ++ci){
    #pragma unroll
    for (int ky = 0; ky < 3; ++ky){
      int yy = Y + ky - 1; if ((unsigned)yy >= 1024u) continue;
      #pragma unroll
      for (int kx = 0; kx < 3; ++kx){
        int xx = X + kx - 1; if ((unsigned)xx >= 2048u) continue;
        int ch = ci*16 + (yy & 3)*4 + (xx & 3);
        s += r1[(((long)bb*64 + ch)*256 + (yy >> 2))*512 + (xx >> 2)] * w[(ci*3 + ky)*3 + kx];
      }
    }
  }
  out[idx] = s;
}

// unpatchify remap + add residual: pred (B,512,4096) + r2 (B,1024,2048) -> ysum
__global__ void ysum_kernel(const float* __restrict__ pred, const float* __restrict__ r2,
                            float* __restrict__ out)
{
  long idx = (long)blockIdx.x*256 + threadIdx.x;   // 4,194,304
  int X = idx & 2047, Y = (idx >> 11) & 1023, bb = (int)(idx >> 21);
  int i2 = Y >> 4, p = Y & 15, j2 = X >> 4, q = X & 15;
  int l = i2*8 + (j2 >> 4);
  int e = (j2 & 15)*256 + p*16 + q;
  out[idx] = pred[((long)bb*512 + l)*4096 + e] + r2[idx];
}

// final 1-channel 3x3 conv -> d_out
__global__ void cout_kernel(const float* __restrict__ ys, const float* __restrict__ w,
                            const float* __restrict__ bi, float* __restrict__ out)
{
  long idx = (long)blockIdx.x*256 + threadIdx.x;   // 4,194,304
  int X = idx & 2047, Y = (idx >> 11) & 1023, bb = (int)(idx >> 21);
  float s = bi[0];
  #pragma unroll
  for (int ky = 0; ky < 3; ++ky){
    int yy = Y + ky - 1; if ((unsigned)yy >= 1024u) continue;
    #pragma unroll
    for (int kx = 0; kx < 3; ++kx){
      int xx = X + kx - 1; if ((unsigned)xx >= 2048u) continue;
      s += ys[((long)bb*1024 + yy)*2048 + xx] * w[ky*3 + kx];
    }
  }
  out[idx] = s;
}

// ---------------------------------------------------------------------------------------
static inline void gemm(hipStream_t st, const float* A, int lda, const float* W, int ldw,
                        const float* bias, const float* res, float* C, int ldc,
                        int M, int N, int K, int batches,
                        long sA, long sW, long sBias, long sRes, long sC,
                        int wmod, int act)
{
  dim3 g(N/64, M/64, batches);
  gemm_f32<<<g, 256, 0, st>>>(A, W, bias, res, C, M, N, K, lda, ldw, ldc,
                              sA, sW, sBias, sRes, sC, wmod, act);
}

extern "C" void kernel_launch(void* const* d_in, const int* in_sizes, int n_in,
                              void* d_out, int out_size, void* d_ws, size_t ws_size,
                              hipStream_t stream)
{
  const float* x         = (const float*)d_in[0];
  const int*   hard_idx  = (const int*)  d_in[1];
  const float* patch_w   = (const float*)d_in[2];
  const float* patch_b   = (const float*)d_in[3];
  const float* var_embed = (const float*)d_in[4];
  const float* var_query = (const float*)d_in[5];
  const float* agg_wq    = (const float*)d_in[6];
  const float* agg_wk    = (const float*)d_in[7];
  const float* agg_wv    = (const float*)d_in[8];
  const float* agg_wo    = (const float*)d_in[9];
  const float* agg_bo    = (const float*)d_in[10];
  const float* pos_embed = (const float*)d_in[11];
  const float* ln1_w     = (const float*)d_in[12];
  const float* ln1_b     = (const float*)d_in[13];
  const float* qkv_w     = (const float*)d_in[14];
  const float* qkv_b     = (const float*)d_in[15];
  const float* aproj_w   = (const float*)d_in[16];
  const float* aproj_b   = (const float*)d_in[17];
  const float* ln2_w     = (const float*)d_in[18];
  const float* ln2_b     = (const float*)d_in[19];
  const float* fc1_w     = (const float*)d_in[20];
  const float* fc1_b     = (const float*)d_in[21];
  const float* fc2_w     = (const float*)d_in[22];
  const float* fc2_b     = (const float*)d_in[23];
  const float* norm_w    = (const float*)d_in[24];
  const float* norm_b    = (const float*)d_in[25];
  const float* head_w    = (const float*)d_in[26];
  const float* head_b    = (const float*)d_in[27];
  const float* head_out_w= (const float*)d_in[28];
  const float* head_out_b= (const float*)d_in[29];
  const float* p2c1_w    = (const float*)d_in[30];
  const float* p2c1_b    = (const float*)d_in[31];
  const float* p2c2_w    = (const float*)d_in[32];
  const float* p2c2_b    = (const float*)d_in[33];
  const float* cout_w    = (const float*)d_in[34];
  const float* cout_b    = (const float*)d_in[35];

  float* ws   = (float*)d_ws;
  float* xt    = ws;               // 1U  (B,512,1024) persistent
  float* r2    = ws + 1*UNIT;      // 4U  (B,1024,2048) persistent
  float* pred  = ws + 5*UNIT;      // 4U  (B,512,4096)
  float* arena = ws + 9*UNIT;      // 17U arena
  float* tail  = ws + 26*UNIT;     // 8192 floats: pb2(4096) + q(1024)
  float* pb2   = tail;
  float* qv    = tail + 4096;

  // ---- Phase 0: residual conv path -> r2 ----
  {
    float* rbig = arena;           // 16U
    conv1_kernel<<<65536, 256, 0, stream>>>(x, p2c1_w, p2c1_b, rbig);
    conv2_kernel<<<16384, 256, 0, stream>>>(rbig, p2c2_w, p2c2_b, r2);
  }

  // ---- Phase 1: patch embed + aggregate variables -> xt ----
  {
    float* xp    = arena;            // 4U
    float* tok   = arena + 4*UNIT;   // 4U
    float* kb    = arena + 8*UNIT;   // 4U
    float* vb    = arena + 12*UNIT;  // 4U
    float* aggin = arena + 16*UNIT;  // 1U

    pb2_combine<<<16, 256, 0, stream>>>(patch_b, var_embed, pb2);
    xp_extract<<<1024, 256, 0, stream>>>(x, xp);
    // tok[b,v,l,:] = xp[b,v,l,:] @ patch_w[v] + pb2[v]   (8 batches, wmod=4)
    gemm(stream, xp, 256, patch_w, 1024, pb2, nullptr, tok, 1024,
         512, 1024, 256, 8, 512L*256, 256L*1024, 1024, 0, 512L*1024, 4, 0);
    qproj<<<16, 64, 0, stream>>>(var_query, agg_wq, qv);
    gemm(stream, tok, 1024, agg_wk, 1024, nullptr, nullptr, kb, 1024,
         512, 1024, 1024, 8, 512L*1024, 0, 0, 0, 512L*1024, 1, 0);
    gemm(stream, tok, 1024, agg_wv, 1024, nullptr, nullptr, vb, 1024,
         512, 1024, 1024, 8, 512L*1024, 0, 0, 0, 512L*1024, 1, 0);
    agg_attn<<<dim3(512, 16, 2), 64, 0, stream>>>(kb, vb, qv, aggin);
    // xt[b] = aggin[b] @ agg_wo + agg_bo + pos_embed
    gemm(stream, aggin, 1024, agg_wo, 1024, agg_bo, pos_embed, xt, 1024,
         512, 1024, 1024, 2, 512L*1024, 0, 0, 0, 512L*1024, 1, 0);
  }

  // ---- Phase 2: transformer blocks ----
  float* hn   = arena;              // 1U
  float* qkvb = arena + 1*UNIT;     // 3U
  float* ao   = arena + 4*UNIT;     // 1U
  float* ff   = arena + 5*UNIT;     // 4U
  float* hbuf = arena + 9*UNIT;     // 0.25U (B,128,1024)

  auto run_block = [&](float* cur, int N, int d){
    int rows = 2 * N;
    ln_kernel<<<rows, 256, 0, stream>>>(cur, ln1_w + d*1024, ln1_b + d*1024, hn);
    gemm(stream, hn, 1024, qkv_w + (long)d*1024*3072, 3072, qkv_b + d*3072, nullptr,
         qkvb, 3072, rows, 3072, 1024, 1, 0, 0, 0, 0, 0, 1, 0);
    attn_kernel<<<dim3(N, 16, 2), 64, 0, stream>>>(qkvb, ao, N);
    gemm(stream, ao, 1024, aproj_w + (long)d*1024*1024, 1024, aproj_b + d*1024, cur,
         cur, 1024, rows, 1024, 1024, 1, 0, 0, 0, 0, 0, 1, 0);
    ln_kernel<<<rows, 256, 0, stream>>>(cur, ln2_w + d*1024, ln2_b + d*1024, hn);
    gemm(stream, hn, 1024, fc1_w + (long)d*1024*4096, 4096, fc1_b + d*4096, nullptr,
         ff, 4096, rows, 4096, 1024, 1, 0, 0, 0, 0, 0, 1, 1);
    gemm(stream, ff, 4096, fc2_w + (long)d*4096*1024, 1024, fc2_b + d*1024, cur,
         cur, 1024, rows, 1024, 4096, 1, 0, 0, 0, 0, 0, 1, 0);
  };

  run_block(xt, 512, 0);
  run_block(xt, 512, 1);
  gather_rows<<<256, 256, 0, stream>>>(xt, hard_idx, hbuf);
  run_block(hbuf, 128, 2);
  run_block(hbuf, 128, 3);
  run_block(hbuf, 128, 4);
  scatter_rows<<<256, 256, 0, stream>>>(hbuf, hard_idx, xt);
  run_block(xt, 512, 5);

  // ---- Phase 3: final LN + head ----
  float* lnout = hn;                // 1U
  float* t1    = qkvb;              // 1U (reuse)
  ln_kernel<<<1024, 256, 0, stream>>>(xt, norm_w, norm_b, lnout);
  gemm(stream, lnout, 1024, head_w, 1024, head_b, nullptr, t1, 1024,
       1024, 1024, 1024, 1, 0, 0, 0, 0, 0, 1, 1);
  gemm(stream, t1, 1024, head_w + 1024L*1024, 1024, head_b + 1024, nullptr, lnout, 1024,
       1024, 1024, 1024, 1, 0, 0, 0, 0, 0, 1, 1);
  gemm(stream, lnout, 1024, head_out_w, 4096, head_out_b, nullptr, pred, 4096,
       1024, 4096, 1024, 1, 0, 0, 0, 0, 0, 1, 0);

  // ---- Phase 4: unpatchify + residual + final conv ----
  float* ysum = arena;              // 4U (block temporaries dead)
  ysum_kernel<<<16384, 256, 0, stream>>>(pred, r2, ysum);
  cout_kernel<<<16384, 256, 0, stream>>>(ysum, cout_w, cout_b, (float*)d_out);
}

// Round 2
// 3693.404 us; speedup vs baseline: 1.6706x; 1.6706x over previous
//
#include <hip/hip_runtime.h>
#include <math.h>

// Res_Slim_ViT_Adaptive — bf16-MFMA GEMMs + flash-tile attention.
// Shapes: P=16 D=1024 NH=16 HD=64 MAG=4 B=2 V=4 H=256 W=512 L=512 KEEP=128 DEPTH=6

#define UNIT 1048576L   // 1M floats

typedef __attribute__((ext_vector_type(8))) short short8;
typedef __attribute__((ext_vector_type(4))) float f32x4;

__device__ __forceinline__ float gelu_f(float v){
  return 0.5f*v*(1.0f + erff(v*0.70710678118654752440f));
}

__device__ __forceinline__ unsigned short f2bf(float f){
  union { float f; unsigned u; } a; a.f = f;
  unsigned r = a.u + 0x7fffu + ((a.u >> 16) & 1u);
  return (unsigned short)(r >> 16);
}

// =============== bf16 MFMA GEMM: C = act(A_bf16 @ W_fp32 + bias + res) ===============
// 128x128 tile, BK=32, 256 threads (4 waves, each 64x64 = 4x4 of 16x16x32 frags).
// A: bf16 [M][K] contiguous. W: fp32 [K][N] (converted to bf16 during staging).
// M mult of 128, N mult of 128, K mult of 32.
__global__ __launch_bounds__(256)
void gemm_bf16(const unsigned short* __restrict__ A, const float* __restrict__ W,
               const float* __restrict__ bias, const float* __restrict__ res,
               float* __restrict__ Cf, unsigned short* __restrict__ Cb,
               int M, int N, int K, int ldw, int ldc,
               long sA, long sW, long sBias, long sRes, long sC,
               int wmod, int act)
{
  int bz = blockIdx.z;
  A += (long)bz * sA;
  int wb = bz % wmod;
  W += (long)wb * sW;
  const float* bptr = bias ? bias + (long)wb * sBias : nullptr;
  const float* rptr = res  ? res  + (long)bz * sRes : nullptr;
  if (Cf) Cf += (long)bz * sC;
  if (Cb) Cb += (long)bz * sC;

  __shared__ __align__(16) unsigned short As[128*32];  // [m][k]
  __shared__ __align__(16) unsigned short Bs[128*32];  // [n][k]

  int t = threadIdx.x;
  int wave = t >> 6, lane = t & 63;
  int ln = lane & 15, kg = lane >> 4;
  int wm = (wave & 1) * 64, wn = (wave >> 1) * 64;
  int row0 = blockIdx.y * 128, col0 = blockIdx.x * 128;

  f32x4 acc[4][4];
  f32x4 z = {0.f, 0.f, 0.f, 0.f};
  #pragma unroll
  for (int i = 0; i < 4; ++i)
    #pragma unroll
    for (int j = 0; j < 4; ++j) acc[i][j] = z;

  int sm = t >> 2;          // 0..63
  int sk = (t & 3) * 8;     // 0,8,16,24
  long l = ldw;

  for (int k0 = 0; k0 < K; k0 += 32){
    #pragma unroll
    for (int rr = 0; rr < 2; ++rr){
      int m = rr*64 + sm;
      // A: bf16 direct copy, 16B per lane, consecutive LDS chunks
      *(uint4*)&As[m*32 + sk] = *(const uint4*)&A[(long)(row0 + m)*K + k0 + sk];
      // B: strided fp32 column reads, cvt->bf16, pack to 16B
      const float* wp = W + (long)(k0 + sk)*l + col0 + m;
      unsigned q0 = (unsigned)f2bf(wp[0])   | ((unsigned)f2bf(wp[l])   << 16);
      unsigned q1 = (unsigned)f2bf(wp[2*l]) | ((unsigned)f2bf(wp[3*l]) << 16);
      unsigned q2 = (unsigned)f2bf(wp[4*l]) | ((unsigned)f2bf(wp[5*l]) << 16);
      unsigned q3 = (unsigned)f2bf(wp[6*l]) | ((unsigned)f2bf(wp[7*l]) << 16);
      uint4 pk = {q0, q1, q2, q3};
      *(uint4*)&Bs[m*32 + sk] = pk;
    }
    __syncthreads();
    short8 af[4], bfg[4];
    #pragma unroll
    for (int i = 0; i < 4; ++i) af[i]  = *(const short8*)&As[(wm + i*16 + ln)*32 + kg*8];
    #pragma unroll
    for (int j = 0; j < 4; ++j) bfg[j] = *(const short8*)&Bs[(wn + j*16 + ln)*32 + kg*8];
    #pragma unroll
    for (int i = 0; i < 4; ++i)
      #pragma unroll
      for (int j = 0; j < 4; ++j)
        acc[i][j] = __builtin_amdgcn_mfma_f32_16x16x32_bf16(af[i], bfg[j], acc[i][j], 0, 0, 0);
    __syncthreads();
  }

  // C/D layout (m89/m91-verified): col = lane&15, row = (lane>>4)*4 + reg
  #pragma unroll
  for (int i = 0; i < 4; ++i){
    int rbase = row0 + wm + i*16 + kg*4;
    #pragma unroll
    for (int j = 0; j < 4; ++j){
      int c = col0 + wn + j*16 + ln;
      float bv = bptr ? bptr[c] : 0.f;
      #pragma unroll
      for (int rr2 = 0; rr2 < 4; ++rr2){
        int rrow = rbase + rr2;
        float v = acc[i][j][rr2] + bv;
        if (rptr) v += rptr[(long)rrow*ldc + c];
        if (act == 1) v = gelu_f(v);
        if (Cf) Cf[(long)rrow*ldc + c] = v;
        if (Cb) Cb[(long)rrow*ldc + c] = f2bf(v);
      }
    }
  }
}

// ---------------- LayerNorm over D=1024 -> bf16 out, one row per block ----------------
__global__ __launch_bounds__(256)
void ln_bf(const float* __restrict__ x, const float* __restrict__ g,
           const float* __restrict__ b, unsigned short* __restrict__ y)
{
  long r = blockIdx.x;
  int t = threadIdx.x;
  float4 v = ((const float4*)(x + r*1024))[t];
  float s  = v.x + v.y + v.z + v.w;
  float ss = v.x*v.x + v.y*v.y + v.z*v.z + v.w*v.w;
  #pragma unroll
  for (int o = 32; o; o >>= 1){ s += __shfl_xor(s, o); ss += __shfl_xor(ss, o); }
  __shared__ float sa[4], sb[4];
  int w = t >> 6, lane = t & 63;
  if (!lane){ sa[w] = s; sb[w] = ss; }
  __syncthreads();
  s  = sa[0] + sa[1] + sa[2] + sa[3];
  ss = sb[0] + sb[1] + sb[2] + sb[3];
  float mean = s * (1.0f/1024.0f);
  float var  = ss * (1.0f/1024.0f) - mean*mean;
  float rstd = rsqrtf(var + 1e-5f);
  float4 gv = ((const float4*)g)[t];
  float4 bv = ((const float4*)b)[t];
  float ox = (v.x-mean)*rstd*gv.x + bv.x;
  float oy = (v.y-mean)*rstd*gv.y + bv.y;
  float oz = (v.z-mean)*rstd*gv.z + bv.z;
  float ow = (v.w-mean)*rstd*gv.w + bv.w;
  unsigned q0 = (unsigned)f2bf(ox) | ((unsigned)f2bf(oy) << 16);
  unsigned q1 = (unsigned)f2bf(oz) | ((unsigned)f2bf(ow) << 16);
  uint2 pk = {q0, q1};
  *(uint2*)&y[r*1024 + t*4] = pk;
}

// ---------------- patch extraction -> bf16: x (B,V,256,512) -> xp (B,V,512,256) -------
__global__ void xp_extract(const float* __restrict__ x, unsigned short* __restrict__ xp)
{
  int idx = blockIdx.x * 256 + threadIdx.x;          // 262144 groups of 4
  int e4 = idx & 63;
  int lt = (idx >> 6) & 511;
  int zz = idx >> 15;
  int e  = e4 << 2;
  int py = e >> 4, px0 = e & 15;
  int hy = lt >> 5, wx = lt & 31;
  float4 v = *(const float4*)&x[((long)zz*256 + hy*16 + py)*512 + wx*16 + px0];
  unsigned q0 = (unsigned)f2bf(v.x) | ((unsigned)f2bf(v.y) << 16);
  unsigned q1 = (unsigned)f2bf(v.z) | ((unsigned)f2bf(v.w) << 16);
  uint2 pk = {q0, q1};
  ((uint2*)xp)[idx] = pk;
}

__global__ void pb2_combine(const float* __restrict__ pb, const float* __restrict__ ve,
                            float* __restrict__ out)
{
  int i = blockIdx.x * 256 + threadIdx.x;            // 4096
  out[i] = pb[i] + ve[i];
}

__global__ void qproj(const float* __restrict__ vq, const float* __restrict__ wq,
                      float* __restrict__ q)
{
  int n = blockIdx.x * 64 + threadIdx.x;             // 1024
  float s = 0.f;
  for (int k = 0; k < 1024; ++k) s += vq[k] * wq[(long)k*1024 + n];
  q[n] = s;
}

// aggregate_variables attention: softmax over V=4 per (b,l,h) -> bf16 out
__global__ __launch_bounds__(64)
void agg_attn(const float* __restrict__ kb, const float* __restrict__ vb,
              const float* __restrict__ q, unsigned short* __restrict__ out)
{
  int lt = blockIdx.x, h = blockIdx.y, b = blockIdx.z, t = threadIdx.x;
  float qd = q[h*64 + t];
  long off[4];
  float s[4];
  #pragma unroll
  for (int v = 0; v < 4; ++v){
    off[v] = ((((long)b*4 + v)*512 + lt)*1024) + h*64 + t;
    float p = qd * kb[off[v]];
    #pragma unroll
    for (int o = 32; o; o >>= 1) p += __shfl_xor(p, o);
    s[v] = p * 0.125f;
  }
  float m = fmaxf(fmaxf(s[0], s[1]), fmaxf(s[2], s[3]));
  float e0 = __expf(s[0]-m), e1 = __expf(s[1]-m), e2 = __expf(s[2]-m), e3 = __expf(s[3]-m);
  float inv = 1.0f / (e0 + e1 + e2 + e3);
  float o = e0*vb[off[0]] + e1*vb[off[1]] + e2*vb[off[2]] + e3*vb[off[3]];
  out[(((long)b*512 + lt)*1024) + h*64 + t] = f2bf(o * inv);
}

// ---------------- flash-tile self-attention: 32 q-rows x 1 head per block -------------
// qkv fp32 (B,N,3072) [q|k|v], out bf16 (B,N,1024). grid (N/32, 16, 2), 256 threads.
__global__ __launch_bounds__(256)
void attn_v2(const float* __restrict__ qkv, unsigned short* __restrict__ out, int N)
{
  int h = blockIdx.y, b = blockIdx.z;
  int row0 = blockIdx.x * 32;
  int t = threadIdx.x;
  int r = t & 31, g = t >> 5;
  int c0 = g * 8;
  const float* base = qkv + (long)b * N * 3072;

  __shared__ float QsT[64][33];   // [d][r]
  __shared__ float KV[64][68];    // K phase: [d][c]; V phase: [j][d]
  __shared__ float Ps[32][65];
  __shared__ float red[32][9], red2[32][9];

  { // Q tile transposed
    const float* qp = base + (long)(row0 + r)*3072 + h*64 + c0;
    float4 a  = *(const float4*)qp;
    float4 bq = *(const float4*)(qp + 4);
    QsT[c0+0][r]=a.x;  QsT[c0+1][r]=a.y;  QsT[c0+2][r]=a.z;  QsT[c0+3][r]=a.w;
    QsT[c0+4][r]=bq.x; QsT[c0+5][r]=bq.y; QsT[c0+6][r]=bq.z; QsT[c0+7][r]=bq.w;
  }
  float m_r = -1e30f, l_r = 0.f;
  float O[8] = {0,0,0,0,0,0,0,0};
  int vc = t & 63, vd = (t >> 6) * 16;

  for (int j0 = 0; j0 < N; j0 += 64){
    __syncthreads();                      // prev PV done; QsT visible (1st iter)
    { // stage K chunk -> KV[d][c]
      const float* kp = base + (long)(j0 + vc)*3072 + 1024 + h*64 + vd;
      float4 k1 = *(const float4*)kp,     k2 = *(const float4*)(kp+4);
      float4 k3 = *(const float4*)(kp+8), k4 = *(const float4*)(kp+12);
      KV[vd+ 0][vc]=k1.x; KV[vd+ 1][vc]=k1.y; KV[vd+ 2][vc]=k1.z; KV[vd+ 3][vc]=k1.w;
      KV[vd+ 4][vc]=k2.x; KV[vd+ 5][vc]=k2.y; KV[vd+ 6][vc]=k2.z; KV[vd+ 7][vc]=k2.w;
      KV[vd+ 8][vc]=k3.x; KV[vd+ 9][vc]=k3.y; KV[vd+10][vc]=k3.z; KV[vd+11][vc]=k3.w;
      KV[vd+12][vc]=k4.x; KV[vd+13][vc]=k4.y; KV[vd+14][vc]=k4.z; KV[vd+15][vc]=k4.w;
    }
    __syncthreads();
    float s[8] = {0,0,0,0,0,0,0,0};
    #pragma unroll 16
    for (int d = 0; d < 64; ++d){
      float q = QsT[d][r];
      float4 k1 = *(const float4*)&KV[d][c0];
      float4 k2 = *(const float4*)&KV[d][c0+4];
      s[0] += q*k1.x; s[1] += q*k1.y; s[2] += q*k1.z; s[3] += q*k1.w;
      s[4] += q*k2.x; s[5] += q*k2.y; s[6] += q*k2.z; s[7] += q*k2.w;
    }
    float lm = -1e30f;
    #pragma unroll
    for (int i = 0; i < 8; ++i){ s[i] *= 0.125f; lm = fmaxf(lm, s[i]); }
    red[r][g] = lm;
    __syncthreads();
    float mc = red[r][0];
    #pragma unroll
    for (int gg = 1; gg < 8; ++gg) mc = fmaxf(mc, red[r][gg]);
    float m_new = fmaxf(m_r, mc);
    float alpha = __expf(m_r - m_new);
    float ls = 0.f;
    #pragma unroll
    for (int i = 0; i < 8; ++i){ float p = __expf(s[i]-m_new); Ps[r][c0+i] = p; ls += p; }
    red2[r][g] = ls;
    __syncthreads();                      // Ps/red2 visible; K reads all done
    float cs = 0.f;
    #pragma unroll
    for (int gg = 0; gg < 8; ++gg) cs += red2[r][gg];
    l_r = alpha*l_r + cs;
    m_r = m_new;
    #pragma unroll
    for (int i = 0; i < 8; ++i) O[i] *= alpha;
    { // stage V chunk -> KV[j][d]
      const float* vp = base + (long)(j0 + vc)*3072 + 2048 + h*64 + vd;
      float4 v1 = *(const float4*)vp,     v2 = *(const float4*)(vp+4);
      float4 v3 = *(const float4*)(vp+8), v4 = *(const float4*)(vp+12);
      *(float4*)&KV[vc][vd]    = v1;
      *(float4*)&KV[vc][vd+4]  = v2;
      *(float4*)&KV[vc][vd+8]  = v3;
      *(float4*)&KV[vc][vd+12] = v4;
    }
    __syncthreads();
    #pragma unroll 16
    for (int j = 0; j < 64; ++j){
      float p = Ps[r][j];
      float4 v1 = *(const float4*)&KV[j][c0];
      float4 v2 = *(const float4*)&KV[j][c0+4];
      O[0] += p*v1.x; O[1] += p*v1.y; O[2] += p*v1.z; O[3] += p*v1.w;
      O[4] += p*v2.x; O[5] += p*v2.y; O[6] += p*v2.z; O[7] += p*v2.w;
    }
  }
  float inv = 1.0f / l_r;
  unsigned q0 = (unsigned)f2bf(O[0]*inv) | ((unsigned)f2bf(O[1]*inv) << 16);
  unsigned q1 = (unsigned)f2bf(O[2]*inv) | ((unsigned)f2bf(O[3]*inv) << 16);
  unsigned q2 = (unsigned)f2bf(O[4]*inv) | ((unsigned)f2bf(O[5]*inv) << 16);
  unsigned q3 = (unsigned)f2bf(O[6]*inv) | ((unsigned)f2bf(O[7]*inv) << 16);
  uint4 pk = {q0, q1, q2, q3};
  *(uint4*)&out[((long)(b*N + row0 + r))*1024 + h*64 + c0] = pk;
}

// gather / scatter 128 hard tokens per batch (fp32 stream)
__global__ __launch_bounds__(256)
void gather_rows(const float* __restrict__ src, const int* __restrict__ idx,
                 float* __restrict__ dst)
{
  int r = blockIdx.x;
  int b = r >> 7, i = r & 127;
  int s = idx[b*128 + i];
  ((float4*)(dst + (long)r*1024))[threadIdx.x] =
      ((const float4*)(src + ((long)b*512 + s)*1024))[threadIdx.x];
}
__global__ __launch_bounds__(256)
void scatter_rows(const float* __restrict__ src, const int* __restrict__ idx,
                  float* __restrict__ dst)
{
  int r = blockIdx.x;
  int b = r >> 7, i = r & 127;
  int s = idx[b*128 + i];
  ((float4*)(dst + ((long)b*512 + s)*1024))[threadIdx.x] =
      ((const float4*)(src + (long)r*1024))[threadIdx.x];
}

// conv1: x (B,4,256,512) -> gelu(conv3x3) -> (B,64,256,512)
__global__ void conv1_kernel(const float* __restrict__ x, const float* __restrict__ w,
                             const float* __restrict__ bi, float* __restrict__ out)
{
  long idx = (long)blockIdx.x*256 + threadIdx.x;
  int px = idx & 511, py = (idx >> 9) & 255, co = (idx >> 17) & 63, bb = (int)(idx >> 23);
  float s = bi[co];
  #pragma unroll
  for (int ci = 0; ci < 4; ++ci){
    const float* xc = x + ((long)(bb*4 + ci)*256)*512;
    const float* wc = w + (co*4 + ci)*9;
    #pragma unroll
    for (int ky = 0; ky < 3; ++ky){
      int yy = py + ky - 1; if ((unsigned)yy >= 256u) continue;
      #pragma unroll
      for (int kx = 0; kx < 3; ++kx){
        int xx = px + kx - 1; if ((unsigned)xx >= 512u) continue;
        s += xc[yy*512 + xx] * wc[ky*3 + kx];
      }
    }
  }
  out[idx] = gelu_f(s);
}

// conv2 fused with pixel_shuffle(r=4): r1 (B,64,256,512) -> (B,1,1024,2048)
__global__ void conv2_kernel(const float* __restrict__ r1, const float* __restrict__ w,
                             const float* __restrict__ bi, float* __restrict__ out)
{
  long idx = (long)blockIdx.x*256 + threadIdx.x;
  int X = idx & 2047, Y = (idx >> 11) & 1023, bb = (int)(idx >> 21);
  float s = bi[0];
  #pragma unroll
  for (int ci = 0; ci < 4; ++ci){
    #pragma unroll
    for (int ky = 0; ky < 3; ++ky){
      int yy = Y + ky - 1; if ((unsigned)yy >= 1024u) continue;
      #pragma unroll
      for (int kx = 0; kx < 3; ++kx){
        int xx = X + kx - 1; if ((unsigned)xx >= 2048u) continue;
        int ch = ci*16 + (yy & 3)*4 + (xx & 3);
        s += r1[(((long)bb*64 + ch)*256 + (yy >> 2))*512 + (xx >> 2)] * w[(ci*3 + ky)*3 + kx];
      }
    }
  }
  out[idx] = s;
}

// unpatchify remap + add residual
__global__ void ysum_kernel(const float* __restrict__ pred, const float* __restrict__ r2,
                            float* __restrict__ out)
{
  long idx = (long)blockIdx.x*256 + threadIdx.x;
  int X = idx & 2047, Y = (idx >> 11) & 1023, bb = (int)(idx >> 21);
  int i2 = Y >> 4, p = Y & 15, j2 = X >> 4, q = X & 15;
  int lt = i2*8 + (j2 >> 4);
  int e = (j2 & 15)*256 + p*16 + q;
  out[idx] = pred[((long)bb*512 + lt)*4096 + e] + r2[idx];
}

// final 1-channel 3x3 conv -> d_out
__global__ void cout_kernel(const float* __restrict__ ys, const float* __restrict__ w,
                            const float* __restrict__ bi, float* __restrict__ out)
{
  long idx = (long)blockIdx.x*256 + threadIdx.x;
  int X = idx & 2047, Y = (idx >> 11) & 1023, bb = (int)(idx >> 21);
  float s = bi[0];
  #pragma unroll
  for (int ky = 0; ky < 3; ++ky){
    int yy = Y + ky - 1; if ((unsigned)yy >= 1024u) continue;
    #pragma unroll
    for (int kx = 0; kx < 3; ++kx){
      int xx = X + kx - 1; if ((unsigned)xx >= 2048u) continue;
      s += ys[((long)bb*1024 + yy)*2048 + xx] * w[ky*3 + kx];
    }
  }
  out[idx] = s;
}

// ---------------------------------------------------------------------------------------
static inline void gemm_bf(hipStream_t st, const unsigned short* A, const float* W,
                           const float* bias, const float* res, float* Cf, unsigned short* Cb,
                           int M, int N, int K, int batches,
                           long sA, long sW, long sBias, long sRes, long sC,
                           int wmod, int act)
{
  dim3 g(N/128, M/128, batches);
  gemm_bf16<<<g, 256, 0, st>>>(A, W, bias, res, Cf, Cb, M, N, K, N, N,
                               sA, sW, sBias, sRes, sC, wmod, act);
}

extern "C" void kernel_launch(void* const* d_in, const int* in_sizes, int n_in,
                              void* d_out, int out_size, void* d_ws, size_t ws_size,
                              hipStream_t stream)
{
  const float* x         = (const float*)d_in[0];
  const int*   hard_idx  = (const int*)  d_in[1];
  const float* patch_w   = (const float*)d_in[2];
  const float* patch_b   = (const float*)d_in[3];
  const float* var_embed = (const float*)d_in[4];
  const float* var_query = (const float*)d_in[5];
  const float* agg_wq    = (const float*)d_in[6];
  const float* agg_wk    = (const float*)d_in[7];
  const float* agg_wv    = (const float*)d_in[8];
  const float* agg_wo    = (const float*)d_in[9];
  const float* agg_bo    = (const float*)d_in[10];
  const float* pos_embed = (const float*)d_in[11];
  const float* ln1_w     = (const float*)d_in[12];
  const float* ln1_b     = (const float*)d_in[13];
  const float* qkv_w     = (const float*)d_in[14];
  const float* qkv_b     = (const float*)d_in[15];
  const float* aproj_w   = (const float*)d_in[16];
  const float* aproj_b   = (const float*)d_in[17];
  const float* ln2_w     = (const float*)d_in[18];
  const float* ln2_b     = (const float*)d_in[19];
  const float* fc1_w     = (const float*)d_in[20];
  const float* fc1_b     = (const float*)d_in[21];
  const float* fc2_w     = (const float*)d_in[22];
  const float* fc2_b     = (const float*)d_in[23];
  const float* norm_w    = (const float*)d_in[24];
  const float* norm_b    = (const float*)d_in[25];
  const float* head_w    = (const float*)d_in[26];
  const float* head_b    = (const float*)d_in[27];
  const float* head_out_w= (const float*)d_in[28];
  const float* head_out_b= (const float*)d_in[29];
  const float* p2c1_w    = (const float*)d_in[30];
  const float* p2c1_b    = (const float*)d_in[31];
  const float* p2c2_w    = (const float*)d_in[32];
  const float* p2c2_b    = (const float*)d_in[33];
  const float* cout_w    = (const float*)d_in[34];
  const float* cout_b    = (const float*)d_in[35];

  float* ws   = (float*)d_ws;
  float* xt    = ws;               // 1U fp32 stream (B,512,1024)
  float* r2    = ws + 1*UNIT;      // 4U
  float* pred  = ws + 5*UNIT;      // 4U
  float* kb    = ws + 9*UNIT;      // 4U (phase1) | rbig 16U (phase0) | ysum 4U (phase4)
  float* vb    = ws + 13*UNIT;     // 4U
  float* qkvb  = ws + 17*UNIT;     // 3U
  float* hbuf  = ws + 20*UNIT;     // 0.25U (B,128,1024)
  unsigned short* b16 = (unsigned short*)(ws + 20*UNIT + UNIT/4);
  unsigned short* hn_bf    = b16;                  // 1M
  unsigned short* ao_bf    = b16 + 1*UNIT;         // 1M
  unsigned short* ff_bf    = b16 + 2*UNIT;         // 4M
  unsigned short* xp_bf    = b16 + 6*UNIT;         // 1M
  unsigned short* tok_bf   = b16 + 7*UNIT;         // 4M
  unsigned short* aggin_bf = b16 + 11*UNIT;        // 1M
  float* tail = ws + 20*UNIT + UNIT/4 + 6*UNIT;    // @26.25U
  float* pb2  = tail;
  float* qv   = tail + 4096;

  // ---- Phase 0: residual conv path -> r2 ----
  {
    float* rbig = kb;              // 16U transient
    conv1_kernel<<<65536, 256, 0, stream>>>(x, p2c1_w, p2c1_b, rbig);
    conv2_kernel<<<16384, 256, 0, stream>>>(rbig, p2c2_w, p2c2_b, r2);
  }

  // ---- Phase 1: patch embed + aggregate variables -> xt ----
  pb2_combine<<<16, 256, 0, stream>>>(patch_b, var_embed, pb2);
  xp_extract<<<1024, 256, 0, stream>>>(x, xp_bf);
  gemm_bf(stream, xp_bf, patch_w, pb2, nullptr, nullptr, tok_bf,
          512, 1024, 256, 8, 512L*256, 256L*1024, 1024, 0, 512L*1024, 4, 0);
  qproj<<<16, 64, 0, stream>>>(var_query, agg_wq, qv);
  gemm_bf(stream, tok_bf, agg_wk, nullptr, nullptr, kb, nullptr,
          512, 1024, 1024, 8, 512L*1024, 0, 0, 0, 512L*1024, 1, 0);
  gemm_bf(stream, tok_bf, agg_wv, nullptr, nullptr, vb, nullptr,
          512, 1024, 1024, 8, 512L*1024, 0, 0, 0, 512L*1024, 1, 0);
  agg_attn<<<dim3(512, 16, 2), 64, 0, stream>>>(kb, vb, qv, aggin_bf);
  gemm_bf(stream, aggin_bf, agg_wo, agg_bo, pos_embed, xt, nullptr,
          512, 1024, 1024, 2, 512L*1024, 0, 0, 0, 512L*1024, 1, 0);

  // ---- Phase 2: transformer blocks ----
  auto run_block = [&](float* cur, int N, int d){
    int rows = 2 * N;
    ln_bf<<<rows, 256, 0, stream>>>(cur, ln1_w + d*1024, ln1_b + d*1024, hn_bf);
    gemm_bf(stream, hn_bf, qkv_w + (long)d*1024*3072, qkv_b + d*3072, nullptr, qkvb, nullptr,
            rows, 3072, 1024, 1, 0, 0, 0, 0, 0, 1, 0);
    attn_v2<<<dim3(N/32, 16, 2), 256, 0, stream>>>(qkvb, ao_bf, N);
    gemm_bf(stream, ao_bf, aproj_w + (long)d*1024*1024, aproj_b + d*1024, cur, cur, nullptr,
            rows, 1024, 1024, 1, 0, 0, 0, 0, 0, 1, 0);
    ln_bf<<<rows, 256, 0, stream>>>(cur, ln2_w + d*1024, ln2_b + d*1024, hn_bf);
    gemm_bf(stream, hn_bf, fc1_w + (long)d*1024*4096, fc1_b + d*4096, nullptr, nullptr, ff_bf,
            rows, 4096, 1024, 1, 0, 0, 0, 0, 0, 1, 1);
    gemm_bf(stream, ff_bf, fc2_w + (long)d*4096*1024, fc2_b + d*1024, cur, cur, nullptr,
            rows, 1024, 4096, 1, 0, 0, 0, 0, 0, 1, 0);
  };

  run_block(xt, 512, 0);
  run_block(xt, 512, 1);
  gather_rows<<<256, 256, 0, stream>>>(xt, hard_idx, hbuf);
  run_block(hbuf, 128, 2);
  run_block(hbuf, 128, 3);
  run_block(hbuf, 128, 4);
  scatter_rows<<<256, 256, 0, stream>>>(hbuf, hard_idx, xt);
  run_block(xt, 512, 5);

  // ---- Phase 3: final LN + head ----
  ln_bf<<<1024, 256, 0, stream>>>(xt, norm_w, norm_b, hn_bf);
  gemm_bf(stream, hn_bf, head_w, head_b, nullptr, nullptr, ao_bf,
          1024, 1024, 1024, 1, 0, 0, 0, 0, 0, 1, 1);
  gemm_bf(stream, ao_bf, head_w + 1024L*1024, head_b + 1024, nullptr, nullptr, hn_bf,
          1024, 1024, 1024, 1, 0, 0, 0, 0, 0, 1, 1);
  gemm_bf(stream, hn_bf, head_out_w, head_out_b, nullptr, pred, nullptr,
          1024, 4096, 1024, 1, 0, 0, 0, 0, 0, 1, 0);

  // ---- Phase 4: unpatchify + residual + final conv ----
  float* ysum = kb;                // 4U, kb dead
  ysum_kernel<<<16384, 256, 0, stream>>>(pred, r2, ysum);
  cout_kernel<<<16384, 256, 0, stream>>>(ysum, cout_w, cout_b, (float*)d_out);
}

// Round 3
// 2267.364 us; speedup vs baseline: 2.7214x; 1.6289x over previous
//
#include <hip/hip_runtime.h>
#include <math.h>

// Res_Slim_ViT_Adaptive — pre-transposed bf16 weights + clean MFMA GEMM.
// Shapes: P=16 D=1024 NH=16 HD=64 MAG=4 B=2 V=4 H=256 W=512 L=512 KEEP=128 DEPTH=6

#define UNIT 1048576L   // 1M elements

typedef __attribute__((ext_vector_type(8))) short short8;
typedef __attribute__((ext_vector_type(4))) float f32x4;

__device__ __forceinline__ float gelu_f(float v){
  return 0.5f*v*(1.0f + erff(v*0.70710678118654752440f));
}

__device__ __forceinline__ unsigned short f2bf(float f){
  union { float f; unsigned u; } a; a.f = f;
  unsigned r = a.u + 0x7fffu + ((a.u >> 16) & 1u);
  return (unsigned short)(r >> 16);
}

// =============== transpose-convert: W fp32 [K][N] -> Wt bf16 [N][K], batched ==========
__global__ __launch_bounds__(256)
void wtrans(const float* __restrict__ W, unsigned short* __restrict__ Wt,
            int K, int N, long sW)
{
  __shared__ float tile[32][33];
  int k0 = blockIdx.y * 32, n0 = blockIdx.x * 32;
  const float* Wp = W + (long)blockIdx.z * sW;
  unsigned short* Wo = Wt + (long)blockIdx.z * sW;
  int tx = threadIdx.x & 31, ty = threadIdx.x >> 5;   // 32 x 8
  #pragma unroll
  for (int i = 0; i < 4; ++i)
    tile[ty*4+i][tx] = Wp[(long)(k0 + ty*4 + i)*N + n0 + tx];
  __syncthreads();
  #pragma unroll
  for (int i = 0; i < 4; ++i){
    int n = ty*4 + i;
    Wo[(long)(n0 + n)*K + k0 + tx] = f2bf(tile[tx][n]);
  }
}

// =============== bf16 MFMA GEMM: C = act(A_bf16 @ Wt_bf16^T + bias + res) =============
// A: bf16 [M][K]; Wt: bf16 [N][K] (pre-transposed). Tile TM x 128, BK=32, 256 threads.
// TM=128: 4 waves 2x2 of 64x64. TM=64: 4 waves side-by-side 64x32.
template<int TM>
__global__ __launch_bounds__(256)
void gemm_bt(const unsigned short* __restrict__ A, const unsigned short* __restrict__ Wt,
             const float* __restrict__ bias, const float* __restrict__ res,
             float* __restrict__ Cf, unsigned short* __restrict__ Cb,
             int M, int N, int K, int ldc,
             long sA, long sW, long sBias, long sRes, long sC,
             int wmod, int act)
{
  constexpr int NJ = (TM == 128) ? 4 : 2;
  int bz = blockIdx.z;
  A += (long)bz * sA;
  int wb = bz % wmod;
  Wt += (long)wb * sW;
  const float* bptr = bias ? bias + (long)wb * sBias : nullptr;
  const float* rptr = res  ? res  + (long)bz * sRes : nullptr;
  if (Cf) Cf += (long)bz * sC;
  if (Cb) Cb += (long)bz * sC;

  __shared__ __align__(16) unsigned short As[TM*32];
  __shared__ __align__(16) unsigned short Bs[128*32];

  int t = threadIdx.x;
  int wave = t >> 6, lane = t & 63;
  int ln = lane & 15, kg = lane >> 4;
  int wm, wn;
  if (TM == 128){ wm = (wave & 1) * 64; wn = (wave >> 1) * 64; }
  else          { wm = 0;               wn = wave * 32; }
  int row0 = blockIdx.y * TM, col0 = blockIdx.x * 128;

  f32x4 acc[4][NJ];
  f32x4 z = {0.f, 0.f, 0.f, 0.f};
  #pragma unroll
  for (int i = 0; i < 4; ++i)
    #pragma unroll
    for (int j = 0; j < NJ; ++j) acc[i][j] = z;

  int sm = t >> 2;          // 0..63
  int sk = (t & 3) * 8;     // 0,8,16,24

  for (int k0 = 0; k0 < K; k0 += 32){
    if (TM == 128){
      #pragma unroll
      for (int rr = 0; rr < 2; ++rr){
        int m = rr*64 + sm;
        *(uint4*)&As[m*32 + sk] = *(const uint4*)&A[(long)(row0 + m)*K + k0 + sk];
      }
    } else {
      *(uint4*)&As[sm*32 + sk] = *(const uint4*)&A[(long)(row0 + sm)*K + k0 + sk];
    }
    #pragma unroll
    for (int rr = 0; rr < 2; ++rr){
      int n = rr*64 + sm;
      *(uint4*)&Bs[n*32 + sk] = *(const uint4*)&Wt[(long)(col0 + n)*K + k0 + sk];
    }
    __syncthreads();
    short8 af[4], bfg[NJ];
    #pragma unroll
    for (int i = 0; i < 4; ++i)  af[i]  = *(const short8*)&As[(wm + i*16 + ln)*32 + kg*8];
    #pragma unroll
    for (int j = 0; j < NJ; ++j) bfg[j] = *(const short8*)&Bs[(wn + j*16 + ln)*32 + kg*8];
    #pragma unroll
    for (int i = 0; i < 4; ++i)
      #pragma unroll
      for (int j = 0; j < NJ; ++j)
        acc[i][j] = __builtin_amdgcn_mfma_f32_16x16x32_bf16(af[i], bfg[j], acc[i][j], 0, 0, 0);
    __syncthreads();
  }

  // C/D layout: col = lane&15, row = (lane>>4)*4 + reg
  #pragma unroll
  for (int i = 0; i < 4; ++i){
    int rbase = row0 + wm + i*16 + kg*4;
    #pragma unroll
    for (int j = 0; j < NJ; ++j){
      int c = col0 + wn + j*16 + ln;
      float bv = bptr ? bptr[c] : 0.f;
      #pragma unroll
      for (int rr2 = 0; rr2 < 4; ++rr2){
        int rrow = rbase + rr2;
        float v = acc[i][j][rr2] + bv;
        if (rptr) v += rptr[(long)rrow*ldc + c];
        if (act == 1) v = gelu_f(v);
        if (Cf) Cf[(long)rrow*ldc + c] = v;
        if (Cb) Cb[(long)rrow*ldc + c] = f2bf(v);
      }
    }
  }
}

// ---------------- LayerNorm over D=1024 -> bf16 out, one row per block ----------------
__global__ __launch_bounds__(256)
void ln_bf(const float* __restrict__ x, const float* __restrict__ g,
           const float* __restrict__ b, unsigned short* __restrict__ y)
{
  long r = blockIdx.x;
  int t = threadIdx.x;
  float4 v = ((const float4*)(x + r*1024))[t];
  float s  = v.x + v.y + v.z + v.w;
  float ss = v.x*v.x + v.y*v.y + v.z*v.z + v.w*v.w;
  #pragma unroll
  for (int o = 32; o; o >>= 1){ s += __shfl_xor(s, o); ss += __shfl_xor(ss, o); }
  __shared__ float sa[4], sb[4];
  int w = t >> 6, lane = t & 63;
  if (!lane){ sa[w] = s; sb[w] = ss; }
  __syncthreads();
  s  = sa[0] + sa[1] + sa[2] + sa[3];
  ss = sb[0] + sb[1] + sb[2] + sb[3];
  float mean = s * (1.0f/1024.0f);
  float var  = ss * (1.0f/1024.0f) - mean*mean;
  float rstd = rsqrtf(var + 1e-5f);
  float4 gv = ((const float4*)g)[t];
  float4 bv = ((const float4*)b)[t];
  float ox = (v.x-mean)*rstd*gv.x + bv.x;
  float oy = (v.y-mean)*rstd*gv.y + bv.y;
  float oz = (v.z-mean)*rstd*gv.z + bv.z;
  float ow = (v.w-mean)*rstd*gv.w + bv.w;
  unsigned q0 = (unsigned)f2bf(ox) | ((unsigned)f2bf(oy) << 16);
  unsigned q1 = (unsigned)f2bf(oz) | ((unsigned)f2bf(ow) << 16);
  uint2 pk = {q0, q1};
  *(uint2*)&y[r*1024 + t*4] = pk;
}

// ---------------- patch extraction -> bf16: x (B,V,256,512) -> xp (B,V,512,256) -------
__global__ void xp_extract(const float* __restrict__ x, unsigned short* __restrict__ xp)
{
  int idx = blockIdx.x * 256 + threadIdx.x;          // 262144 groups of 4
  int e4 = idx & 63;
  int lt = (idx >> 6) & 511;
  int zz = idx >> 15;
  int e  = e4 << 2;
  int py = e >> 4, px0 = e & 15;
  int hy = lt >> 5, wx = lt & 31;
  float4 v = *(const float4*)&x[((long)zz*256 + hy*16 + py)*512 + wx*16 + px0];
  unsigned q0 = (unsigned)f2bf(v.x) | ((unsigned)f2bf(v.y) << 16);
  unsigned q1 = (unsigned)f2bf(v.z) | ((unsigned)f2bf(v.w) << 16);
  uint2 pk = {q0, q1};
  ((uint2*)xp)[idx] = pk;
}

__global__ void pb2_combine(const float* __restrict__ pb, const float* __restrict__ ve,
                            float* __restrict__ out)
{
  int i = blockIdx.x * 256 + threadIdx.x;            // 4096
  out[i] = pb[i] + ve[i];
}

__global__ void qproj(const float* __restrict__ vq, const float* __restrict__ wq,
                      float* __restrict__ q)
{
  int n = blockIdx.x * 64 + threadIdx.x;             // 1024
  float s = 0.f;
  for (int k = 0; k < 1024; ++k) s += vq[k] * wq[(long)k*1024 + n];
  q[n] = s;
}

// aggregate_variables attention: softmax over V=4 per (b,l,h) -> bf16 out
__global__ __launch_bounds__(64)
void agg_attn(const float* __restrict__ kb, const float* __restrict__ vb,
              const float* __restrict__ q, unsigned short* __restrict__ out)
{
  int lt = blockIdx.x, h = blockIdx.y, b = blockIdx.z, t = threadIdx.x;
  float qd = q[h*64 + t];
  long off[4];
  float s[4];
  #pragma unroll
  for (int v = 0; v < 4; ++v){
    off[v] = ((((long)b*4 + v)*512 + lt)*1024) + h*64 + t;
    float p = qd * kb[off[v]];
    #pragma unroll
    for (int o = 32; o; o >>= 1) p += __shfl_xor(p, o);
    s[v] = p * 0.125f;
  }
  float m = fmaxf(fmaxf(s[0], s[1]), fmaxf(s[2], s[3]));
  float e0 = __expf(s[0]-m), e1 = __expf(s[1]-m), e2 = __expf(s[2]-m), e3 = __expf(s[3]-m);
  float inv = 1.0f / (e0 + e1 + e2 + e3);
  float o = e0*vb[off[0]] + e1*vb[off[1]] + e2*vb[off[2]] + e3*vb[off[3]];
  out[(((long)b*512 + lt)*1024) + h*64 + t] = f2bf(o * inv);
}

// ---------------- flash-tile self-attention: 32 q-rows x 1 head per block -------------
__global__ __launch_bounds__(256)
void attn_v2(const float* __restrict__ qkv, unsigned short* __restrict__ out, int N)
{
  int h = blockIdx.y, b = blockIdx.z;
  int row0 = blockIdx.x * 32;
  int t = threadIdx.x;
  int r = t & 31, g = t >> 5;
  int c0 = g * 8;
  const float* base = qkv + (long)b * N * 3072;

  __shared__ float QsT[64][33];
  __shared__ float KV[64][68];
  __shared__ float Ps[32][65];
  __shared__ float red[32][9], red2[32][9];

  {
    const float* qp = base + (long)(row0 + r)*3072 + h*64 + c0;
    float4 a  = *(const float4*)qp;
    float4 bq = *(const float4*)(qp + 4);
    QsT[c0+0][r]=a.x;  QsT[c0+1][r]=a.y;  QsT[c0+2][r]=a.z;  QsT[c0+3][r]=a.w;
    QsT[c0+4][r]=bq.x; QsT[c0+5][r]=bq.y; QsT[c0+6][r]=bq.z; QsT[c0+7][r]=bq.w;
  }
  float m_r = -1e30f, l_r = 0.f;
  float O[8] = {0,0,0,0,0,0,0,0};
  int vc = t & 63, vd = (t >> 6) * 16;

  for (int j0 = 0; j0 < N; j0 += 64){
    __syncthreads();
    {
      const float* kp = base + (long)(j0 + vc)*3072 + 1024 + h*64 + vd;
      float4 k1 = *(const float4*)kp,     k2 = *(const float4*)(kp+4);
      float4 k3 = *(const float4*)(kp+8), k4 = *(const float4*)(kp+12);
      KV[vd+ 0][vc]=k1.x; KV[vd+ 1][vc]=k1.y; KV[vd+ 2][vc]=k1.z; KV[vd+ 3][vc]=k1.w;
      KV[vd+ 4][vc]=k2.x; KV[vd+ 5][vc]=k2.y; KV[vd+ 6][vc]=k2.z; KV[vd+ 7][vc]=k2.w;
      KV[vd+ 8][vc]=k3.x; KV[vd+ 9][vc]=k3.y; KV[vd+10][vc]=k3.z; KV[vd+11][vc]=k3.w;
      KV[vd+12][vc]=k4.x; KV[vd+13][vc]=k4.y; KV[vd+14][vc]=k4.z; KV[vd+15][vc]=k4.w;
    }
    __syncthreads();
    float s[8] = {0,0,0,0,0,0,0,0};
    #pragma unroll 16
    for (int d = 0; d < 64; ++d){
      float q = QsT[d][r];
      float4 k1 = *(const float4*)&KV[d][c0];
      float4 k2 = *(const float4*)&KV[d][c0+4];
      s[0] += q*k1.x; s[1] += q*k1.y; s[2] += q*k1.z; s[3] += q*k1.w;
      s[4] += q*k2.x; s[5] += q*k2.y; s[6] += q*k2.z; s[7] += q*k2.w;
    }
    float lm = -1e30f;
    #pragma unroll
    for (int i = 0; i < 8; ++i){ s[i] *= 0.125f; lm = fmaxf(lm, s[i]); }
    red[r][g] = lm;
    __syncthreads();
    float mc = red[r][0];
    #pragma unroll
    for (int gg = 1; gg < 8; ++gg) mc = fmaxf(mc, red[r][gg]);
    float m_new = fmaxf(m_r, mc);
    float alpha = __expf(m_r - m_new);
    float ls = 0.f;
    #pragma unroll
    for (int i = 0; i < 8; ++i){ float p = __expf(s[i]-m_new); Ps[r][c0+i] = p; ls += p; }
    red2[r][g] = ls;
    __syncthreads();
    float cs = 0.f;
    #pragma unroll
    for (int gg = 0; gg < 8; ++gg) cs += red2[r][gg];
    l_r = alpha*l_r + cs;
    m_r = m_new;
    #pragma unroll
    for (int i = 0; i < 8; ++i) O[i] *= alpha;
    {
      const float* vp = base + (long)(j0 + vc)*3072 + 2048 + h*64 + vd;
      float4 v1 = *(const float4*)vp,     v2 = *(const float4*)(vp+4);
      float4 v3 = *(const float4*)(vp+8), v4 = *(const float4*)(vp+12);
      *(float4*)&KV[vc][vd]    = v1;
      *(float4*)&KV[vc][vd+4]  = v2;
      *(float4*)&KV[vc][vd+8]  = v3;
      *(float4*)&KV[vc][vd+12] = v4;
    }
    __syncthreads();
    #pragma unroll 16
    for (int j = 0; j < 64; ++j){
      float p = Ps[r][j];
      float4 v1 = *(const float4*)&KV[j][c0];
      float4 v2 = *(const float4*)&KV[j][c0+4];
      O[0] += p*v1.x; O[1] += p*v1.y; O[2] += p*v1.z; O[3] += p*v1.w;
      O[4] += p*v2.x; O[5] += p*v2.y; O[6] += p*v2.z; O[7] += p*v2.w;
    }
  }
  float inv = 1.0f / l_r;
  unsigned q0 = (unsigned)f2bf(O[0]*inv) | ((unsigned)f2bf(O[1]*inv) << 16);
  unsigned q1 = (unsigned)f2bf(O[2]*inv) | ((unsigned)f2bf(O[3]*inv) << 16);
  unsigned q2 = (unsigned)f2bf(O[4]*inv) | ((unsigned)f2bf(O[5]*inv) << 16);
  unsigned q3 = (unsigned)f2bf(O[6]*inv) | ((unsigned)f2bf(O[7]*inv) << 16);
  uint4 pk = {q0, q1, q2, q3};
  *(uint4*)&out[((long)(b*N + row0 + r))*1024 + h*64 + c0] = pk;
}

// gather / scatter 128 hard tokens per batch (fp32 stream)
__global__ __launch_bounds__(256)
void gather_rows(const float* __restrict__ src, const int* __restrict__ idx,
                 float* __restrict__ dst)
{
  int r = blockIdx.x;
  int b = r >> 7, i = r & 127;
  int s = idx[b*128 + i];
  ((float4*)(dst + (long)r*1024))[threadIdx.x] =
      ((const float4*)(src + ((long)b*512 + s)*1024))[threadIdx.x];
}
__global__ __launch_bounds__(256)
void scatter_rows(const float* __restrict__ src, const int* __restrict__ idx,
                  float* __restrict__ dst)
{
  int r = blockIdx.x;
  int b = r >> 7, i = r & 127;
  int s = idx[b*128 + i];
  ((float4*)(dst + ((long)b*512 + s)*1024))[threadIdx.x] =
      ((const float4*)(src + (long)r*1024))[threadIdx.x];
}

// conv1: x (B,4,256,512) -> gelu(conv3x3) -> (B,64,256,512)
__global__ void conv1_kernel(const float* __restrict__ x, const float* __restrict__ w,
                             const float* __restrict__ bi, float* __restrict__ out)
{
  long idx = (long)blockIdx.x*256 + threadIdx.x;
  int px = idx & 511, py = (idx >> 9) & 255, co = (idx >> 17) & 63, bb = (int)(idx >> 23);
  float s = bi[co];
  #pragma unroll
  for (int ci = 0; ci < 4; ++ci){
    const float* xc = x + ((long)(bb*4 + ci)*256)*512;
    const float* wc = w + (co*4 + ci)*9;
    #pragma unroll
    for (int ky = 0; ky < 3; ++ky){
      int yy = py + ky - 1; if ((unsigned)yy >= 256u) continue;
      #pragma unroll
      for (int kx = 0; kx < 3; ++kx){
        int xx = px + kx - 1; if ((unsigned)xx >= 512u) continue;
        s += xc[yy*512 + xx] * wc[ky*3 + kx];
      }
    }
  }
  out[idx] = gelu_f(s);
}

// conv2 fused with pixel_shuffle(r=4): r1 (B,64,256,512) -> (B,1,1024,2048)
__global__ void conv2_kernel(const float* __restrict__ r1, const float* __restrict__ w,
                             const float* __restrict__ bi, float* __restrict__ out)
{
  long idx = (long)blockIdx.x*256 + threadIdx.x;
  int X = idx & 2047, Y = (idx >> 11) & 1023, bb = (int)(idx >> 21);
  float s = bi[0];
  #pragma unroll
  for (int ci = 0; ci < 4; ++ci){
    #pragma unroll
    for (int ky = 0; ky < 3; ++ky){
      int yy = Y + ky - 1; if ((unsigned)yy >= 1024u) continue;
      #pragma unroll
      for (int kx = 0; kx < 3; ++kx){
        int xx = X + kx - 1; if ((unsigned)xx >= 2048u) continue;
        int ch = ci*16 + (yy & 3)*4 + (xx & 3);
        s += r1[(((long)bb*64 + ch)*256 + (yy >> 2))*512 + (xx >> 2)] * w[(ci*3 + ky)*3 + kx];
      }
    }
  }
  out[idx] = s;
}

// unpatchify remap + add residual
__global__ void ysum_kernel(const float* __restrict__ pred, const float* __restrict__ r2,
                            float* __restrict__ out)
{
  long idx = (long)blockIdx.x*256 + threadIdx.x;
  int X = idx & 2047, Y = (idx >> 11) & 1023, bb = (int)(idx >> 21);
  int i2 = Y >> 4, p = Y & 15, j2 = X >> 4, q = X & 15;
  int lt = i2*8 + (j2 >> 4);
  int e = (j2 & 15)*256 + p*16 + q;
  out[idx] = pred[((long)bb*512 + lt)*4096 + e] + r2[idx];
}

// final 1-channel 3x3 conv -> d_out
__global__ void cout_kernel(const float* __restrict__ ys, const float* __restrict__ w,
                            const float* __restrict__ bi, float* __restrict__ out)
{
  long idx = (long)blockIdx.x*256 + threadIdx.x;
  int X = idx & 2047, Y = (idx >> 11) & 1023, bb = (int)(idx >> 21);
  float s = bi[0];
  #pragma unroll
  for (int ky = 0; ky < 3; ++ky){
    int yy = Y + ky - 1; if ((unsigned)yy >= 1024u) continue;
    #pragma unroll
    for (int kx = 0; kx < 3; ++kx){
      int xx = X + kx - 1; if ((unsigned)xx >= 2048u) continue;
      s += ys[((long)bb*1024 + yy)*2048 + xx] * w[ky*3 + kx];
    }
  }
  out[idx] = s;
}

// ---------------------------------------------------------------------------------------
static inline void wtrans_go(hipStream_t st, const float* W, unsigned short* Wt,
                             int K, int N, int batch)
{
  dim3 g(N/32, K/32, batch);
  wtrans<<<g, 256, 0, st>>>(W, Wt, K, N, (long)K*N);
}

static inline void gemm_go(hipStream_t st, int TM, const unsigned short* A,
                           const unsigned short* Wt,
                           const float* bias, const float* res, float* Cf, unsigned short* Cb,
                           int M, int N, int K, int batches,
                           long sA, long sW, long sBias, long sRes, long sC,
                           int wmod, int act)
{
  dim3 g(N/128, M/TM, batches);
  if (TM == 128)
    gemm_bt<128><<<g, 256, 0, st>>>(A, Wt, bias, res, Cf, Cb, M, N, K, N,
                                    sA, sW, sBias, sRes, sC, wmod, act);
  else
    gemm_bt<64><<<g, 256, 0, st>>>(A, Wt, bias, res, Cf, Cb, M, N, K, N,
                                   sA, sW, sBias, sRes, sC, wmod, act);
}

extern "C" void kernel_launch(void* const* d_in, const int* in_sizes, int n_in,
                              void* d_out, int out_size, void* d_ws, size_t ws_size,
                              hipStream_t stream)
{
  const float* x         = (const float*)d_in[0];
  const int*   hard_idx  = (const int*)  d_in[1];
  const float* patch_w   = (const float*)d_in[2];
  const float* patch_b   = (const float*)d_in[3];
  const float* var_embed = (const float*)d_in[4];
  const float* var_query = (const float*)d_in[5];
  const float* agg_wq    = (const float*)d_in[6];
  const float* agg_wk    = (const float*)d_in[7];
  const float* agg_wv    = (const float*)d_in[8];
  const float* agg_wo    = (const float*)d_in[9];
  const float* agg_bo    = (const float*)d_in[10];
  const float* pos_embed = (const float*)d_in[11];
  const float* ln1_w     = (const float*)d_in[12];
  const float* ln1_b     = (const float*)d_in[13];
  const float* qkv_w     = (const float*)d_in[14];
  const float* qkv_b     = (const float*)d_in[15];
  const float* aproj_w   = (const float*)d_in[16];
  const float* aproj_b   = (const float*)d_in[17];
  const float* ln2_w     = (const float*)d_in[18];
  const float* ln2_b     = (const float*)d_in[19];
  const float* fc1_w     = (const float*)d_in[20];
  const float* fc1_b     = (const float*)d_in[21];
  const float* fc2_w     = (const float*)d_in[22];
  const float* fc2_b     = (const float*)d_in[23];
  const float* norm_w    = (const float*)d_in[24];
  const float* norm_b    = (const float*)d_in[25];
  const float* head_w    = (const float*)d_in[26];
  const float* head_b    = (const float*)d_in[27];
  const float* head_out_w= (const float*)d_in[28];
  const float* head_out_b= (const float*)d_in[29];
  const float* p2c1_w    = (const float*)d_in[30];
  const float* p2c1_b    = (const float*)d_in[31];
  const float* p2c2_w    = (const float*)d_in[32];
  const float* p2c2_b    = (const float*)d_in[33];
  const float* cout_w    = (const float*)d_in[34];
  const float* cout_b    = (const float*)d_in[35];

  float* ws = (float*)d_ws;
  float* xt   = ws;               // 1U fp32 stream (B,512,1024)
  float* r2   = ws + 1*UNIT;      // 4U
  float* qkvb = ws + 5*UNIT;      // 3U fp32 qkv
  float* kb   = ws + 8*UNIT;      // 4U (phase1)  -> pred (phase3/4)
  float* pred = ws + 8*UNIT;
  float* vb   = ws + 12*UNIT;     // 4U (phase1)  -> ysum (phase4)
  float* ysum = ws + 12*UNIT;
  float* rbig = ws + 8*UNIT;      // 16U (phase0 only, 8..24U)
  unsigned short* b16 = (unsigned short*)(ws + 16*UNIT);   // 16M ushorts (16..24U)
  unsigned short* hn_bf    = b16;                // 1M
  unsigned short* ao_bf    = b16 + 1*UNIT;       // 1M
  unsigned short* ff_bf    = b16 + 2*UNIT;       // 4M
  unsigned short* xp_bf    = b16 + 6*UNIT;       // 1M
  unsigned short* tok_bf   = b16 + 7*UNIT;       // 4M
  unsigned short* aggin_bf = b16 + 11*UNIT;      // 1M
  unsigned short* wt_bf    = b16 + 12*UNIT;      // 4M (rotating transposed-weight slot)
  float* tail = ws + 24*UNIT;
  float* pb2  = tail;             // 4096
  float* qv   = tail + 4096;      // 1024
  float* hbuf = tail + 8192;      // 0.25U (B,128,1024)

  // ---- Phase 0: residual conv path -> r2 ----
  conv1_kernel<<<65536, 256, 0, stream>>>(x, p2c1_w, p2c1_b, rbig);
  conv2_kernel<<<16384, 256, 0, stream>>>(rbig, p2c2_w, p2c2_b, r2);

  // ---- Phase 1: patch embed + aggregate variables -> xt ----
  pb2_combine<<<16, 256, 0, stream>>>(patch_b, var_embed, pb2);
  xp_extract<<<1024, 256, 0, stream>>>(x, xp_bf);
  wtrans_go(stream, patch_w, wt_bf, 256, 1024, 4);
  gemm_go(stream, 128, xp_bf, wt_bf, pb2, nullptr, nullptr, tok_bf,
          512, 1024, 256, 8, 512L*256, 256L*1024, 1024, 0, 512L*1024, 4, 0);
  qproj<<<16, 64, 0, stream>>>(var_query, agg_wq, qv);
  wtrans_go(stream, agg_wk, wt_bf, 1024, 1024, 1);
  gemm_go(stream, 128, tok_bf, wt_bf, nullptr, nullptr, kb, nullptr,
          512, 1024, 1024, 8, 512L*1024, 0, 0, 0, 512L*1024, 1, 0);
  wtrans_go(stream, agg_wv, wt_bf, 1024, 1024, 1);
  gemm_go(stream, 128, tok_bf, wt_bf, nullptr, nullptr, vb, nullptr,
          512, 1024, 1024, 8, 512L*1024, 0, 0, 0, 512L*1024, 1, 0);
  agg_attn<<<dim3(512, 16, 2), 64, 0, stream>>>(kb, vb, qv, aggin_bf);
  wtrans_go(stream, agg_wo, wt_bf, 1024, 1024, 1);
  gemm_go(stream, 64, aggin_bf, wt_bf, agg_bo, pos_embed, xt, nullptr,
          512, 1024, 1024, 2, 512L*1024, 0, 0, 0, 512L*1024, 1, 0);

  // ---- Phase 2: transformer blocks ----
  auto run_block = [&](float* cur, int Nt, int d){
    int rows = 2 * Nt;
    int TMbig = (rows >= 1024) ? 128 : 64;
    ln_bf<<<rows, 256, 0, stream>>>(cur, ln1_w + d*1024, ln1_b + d*1024, hn_bf);
    wtrans_go(stream, qkv_w + (long)d*1024*3072, wt_bf, 1024, 3072, 1);
    gemm_go(stream, TMbig, hn_bf, wt_bf, qkv_b + d*3072, nullptr, qkvb, nullptr,
            rows, 3072, 1024, 1, 0, 0, 0, 0, 0, 1, 0);
    attn_v2<<<dim3(Nt/32, 16, 2), 256, 0, stream>>>(qkvb, ao_bf, Nt);
    wtrans_go(stream, aproj_w + (long)d*1024*1024, wt_bf, 1024, 1024, 1);
    gemm_go(stream, 64, ao_bf, wt_bf, aproj_b + d*1024, cur, cur, nullptr,
            rows, 1024, 1024, 1, 0, 0, 0, 0, 0, 1, 0);
    ln_bf<<<rows, 256, 0, stream>>>(cur, ln2_w + d*1024, ln2_b + d*1024, hn_bf);
    wtrans_go(stream, fc1_w + (long)d*1024*4096, wt_bf, 1024, 4096, 1);
    gemm_go(stream, TMbig, hn_bf, wt_bf, fc1_b + d*4096, nullptr, nullptr, ff_bf,
            rows, 4096, 1024, 1, 0, 0, 0, 0, 0, 1, 1);
    wtrans_go(stream, fc2_w + (long)d*4096*1024, wt_bf, 4096, 1024, 1);
    gemm_go(stream, 64, ff_bf, wt_bf, fc2_b + d*1024, cur, cur, nullptr,
            rows, 1024, 4096, 1, 0, 0, 0, 0, 0, 1, 0);
  };

  run_block(xt, 512, 0);
  run_block(xt, 512, 1);
  gather_rows<<<256, 256, 0, stream>>>(xt, hard_idx, hbuf);
  run_block(hbuf, 128, 2);
  run_block(hbuf, 128, 3);
  run_block(hbuf, 128, 4);
  scatter_rows<<<256, 256, 0, stream>>>(hbuf, hard_idx, xt);
  run_block(xt, 512, 5);

  // ---- Phase 3: final LN + head ----
  ln_bf<<<1024, 256, 0, stream>>>(xt, norm_w, norm_b, hn_bf);
  wtrans_go(stream, head_w, wt_bf, 1024, 1024, 1);
  gemm_go(stream, 64, hn_bf, wt_bf, head_b, nullptr, nullptr, ao_bf,
          1024, 1024, 1024, 1, 0, 0, 0, 0, 0, 1, 1);
  wtrans_go(stream, head_w + 1024L*1024, wt_bf, 1024, 1024, 1);
  gemm_go(stream, 64, ao_bf, wt_bf, head_b + 1024, nullptr, nullptr, hn_bf,
          1024, 1024, 1024, 1, 0, 0, 0, 0, 0, 1, 1);
  wtrans_go(stream, head_out_w, wt_bf, 1024, 4096, 1);
  gemm_go(stream, 128, hn_bf, wt_bf, head_out_b, nullptr, pred, nullptr,
          1024, 4096, 1024, 1, 0, 0, 0, 0, 0, 1, 0);

  // ---- Phase 4: unpatchify + residual + final conv ----
  ysum_kernel<<<16384, 256, 0, stream>>>(pred, r2, ysum);
  cout_kernel<<<16384, 256, 0, stream>>>(ysum, cout_w, cout_b, (float*)d_out);
}

// Round 4
// 2029.064 us; speedup vs baseline: 3.0410x; 1.1174x over previous
//
#include <hip/hip_runtime.h>
#include <math.h>

// Res_Slim_ViT_Adaptive — r4: conv rewrite (channels-last + LDS tiles), fused epilogue,
// folded aggregation-K, global_load_lds GEMM staging.
// Shapes: P=16 D=1024 NH=16 HD=64 MAG=4 B=2 V=4 H=256 W=512 L=512 KEEP=128 DEPTH=6

#define UNIT 1048576L   // 1M elements

typedef __attribute__((ext_vector_type(8))) short short8;
typedef __attribute__((ext_vector_type(4))) float f32x4;

#define GLDS(gp, lp) __builtin_amdgcn_global_load_lds( \
    (const __attribute__((address_space(1))) void*)(gp), \
    (__attribute__((address_space(3))) void*)(lp), 16, 0, 0)

__device__ __forceinline__ float gelu_f(float v){
  return 0.5f*v*(1.0f + erff(v*0.70710678118654752440f));
}

__device__ __forceinline__ unsigned short f2bf(float f){
  union { float f; unsigned u; } a; a.f = f;
  unsigned r = a.u + 0x7fffu + ((a.u >> 16) & 1u);
  return (unsigned short)(r >> 16);
}
__device__ __forceinline__ float bf2f(unsigned short u){
  union { unsigned u; float f; } a; a.u = (unsigned)u << 16;
  return a.f;
}

// =============== transpose-convert: W fp32 [K][N] -> Wt bf16 [N][K], batched ==========
__global__ __launch_bounds__(256)
void wtrans(const float* __restrict__ W, unsigned short* __restrict__ Wt,
            int K, int N, long sW)
{
  __shared__ float tile[32][33];
  int k0 = blockIdx.y * 32, n0 = blockIdx.x * 32;
  const float* Wp = W + (long)blockIdx.z * sW;
  unsigned short* Wo = Wt + (long)blockIdx.z * sW;
  int tx = threadIdx.x & 31, ty = threadIdx.x >> 5;   // 32 x 8
  #pragma unroll
  for (int i = 0; i < 4; ++i)
    tile[ty*4+i][tx] = Wp[(long)(k0 + ty*4 + i)*N + n0 + tx];
  __syncthreads();
  #pragma unroll
  for (int i = 0; i < 4; ++i){
    int n = ty*4 + i;
    Wo[(long)(n0 + n)*K + k0 + tx] = f2bf(tile[tx][n]);
  }
}

// =============== bf16 MFMA GEMM: C = act(A_bf16 @ Wt_bf16^T + bias + res) =============
// A: bf16 [M][K]; Wt: bf16 [N][K]. Tile TM x 128, BK=32, 256 threads.
// Staging via global_load_lds (lane-linear 16B chunks, no padding).
template<int TM>
__global__ __launch_bounds__(256)
void gemm_bt(const unsigned short* __restrict__ A, const unsigned short* __restrict__ Wt,
             const float* __restrict__ bias, const float* __restrict__ res,
             float* __restrict__ Cf, unsigned short* __restrict__ Cb,
             int M, int N, int K, int ldc,
             long sA, long sW, long sBias, long sRes, long sC,
             int wmod, int act)
{
  constexpr int NJ = (TM == 128) ? 4 : 2;
  int bz = blockIdx.z;
  A += (long)bz * sA;
  int wb = bz % wmod;
  Wt += (long)wb * sW;
  const float* bptr = bias ? bias + (long)wb * sBias : nullptr;
  const float* rptr = res  ? res  + (long)bz * sRes : nullptr;
  if (Cf) Cf += (long)bz * sC;
  if (Cb) Cb += (long)bz * sC;

  __shared__ __align__(16) unsigned short As[TM*32];
  __shared__ __align__(16) unsigned short Bs[128*32];

  int t = threadIdx.x;
  int wave = t >> 6, lane = t & 63;
  int ln = lane & 15, kg = lane >> 4;
  int wm, wn;
  if (TM == 128){ wm = (wave & 1) * 64; wn = (wave >> 1) * 64; }
  else          { wm = 0;               wn = wave * 32; }
  int row0 = blockIdx.y * TM, col0 = blockIdx.x * 128;

  f32x4 acc[4][NJ];
  f32x4 z = {0.f, 0.f, 0.f, 0.f};
  #pragma unroll
  for (int i = 0; i < 4; ++i)
    #pragma unroll
    for (int j = 0; j < NJ; ++j) acc[i][j] = z;

  int sm = t >> 2;          // 0..63
  int sk = (t & 3) * 8;     // halfword offset 0,8,16,24
  unsigned short* AsB = As + wave*512;   // per-wave lane-linear base (512 hw = 1KB)
  unsigned short* BsB = Bs + wave*512;

  for (int k0 = 0; k0 < K; k0 += 32){
    if (TM == 128){
      GLDS(&A[(long)(row0 + sm)*K + k0 + sk],      AsB);
      GLDS(&A[(long)(row0 + 64 + sm)*K + k0 + sk], AsB + 2048);
    } else {
      GLDS(&A[(long)(row0 + sm)*K + k0 + sk],      AsB);
    }
    GLDS(&Wt[(long)(col0 + sm)*K + k0 + sk],      BsB);
    GLDS(&Wt[(long)(col0 + 64 + sm)*K + k0 + sk], BsB + 2048);
    __syncthreads();
    short8 af[4], bfg[NJ];
    #pragma unroll
    for (int i = 0; i < 4; ++i)  af[i]  = *(const short8*)&As[(wm + i*16 + ln)*32 + kg*8];
    #pragma unroll
    for (int j = 0; j < NJ; ++j) bfg[j] = *(const short8*)&Bs[(wn + j*16 + ln)*32 + kg*8];
    #pragma unroll
    for (int i = 0; i < 4; ++i)
      #pragma unroll
      for (int j = 0; j < NJ; ++j)
        acc[i][j] = __builtin_amdgcn_mfma_f32_16x16x32_bf16(af[i], bfg[j], acc[i][j], 0, 0, 0);
    __syncthreads();
  }

  // C/D layout: col = lane&15, row = (lane>>4)*4 + reg
  #pragma unroll
  for (int i = 0; i < 4; ++i){
    int rbase = row0 + wm + i*16 + kg*4;
    #pragma unroll
    for (int j = 0; j < NJ; ++j){
      int c = col0 + wn + j*16 + ln;
      float bv = bptr ? bptr[c] : 0.f;
      #pragma unroll
      for (int rr2 = 0; rr2 < 4; ++rr2){
        int rrow = rbase + rr2;
        float v = acc[i][j][rr2] + bv;
        if (rptr) v += rptr[(long)rrow*ldc + c];
        if (act == 1) v = gelu_f(v);
        if (Cf) Cf[(long)rrow*ldc + c] = v;
        if (Cb) Cb[(long)rrow*ldc + c] = f2bf(v);
      }
    }
  }
}

// ---------------- LayerNorm over D=1024 -> bf16 out, one row per block ----------------
__global__ __launch_bounds__(256)
void ln_bf(const float* __restrict__ x, const float* __restrict__ g,
           const float* __restrict__ b, unsigned short* __restrict__ y)
{
  long r = blockIdx.x;
  int t = threadIdx.x;
  float4 v = ((const float4*)(x + r*1024))[t];
  float s  = v.x + v.y + v.z + v.w;
  float ss = v.x*v.x + v.y*v.y + v.z*v.z + v.w*v.w;
  #pragma unroll
  for (int o = 32; o; o >>= 1){ s += __shfl_xor(s, o); ss += __shfl_xor(ss, o); }
  __shared__ float sa[4], sb[4];
  int w = t >> 6, lane = t & 63;
  if (!lane){ sa[w] = s; sb[w] = ss; }
  __syncthreads();
  s  = sa[0] + sa[1] + sa[2] + sa[3];
  ss = sb[0] + sb[1] + sb[2] + sb[3];
  float mean = s * (1.0f/1024.0f);
  float var  = ss * (1.0f/1024.0f) - mean*mean;
  float rstd = rsqrtf(var + 1e-5f);
  float4 gv = ((const float4*)g)[t];
  float4 bv = ((const float4*)b)[t];
  float ox = (v.x-mean)*rstd*gv.x + bv.x;
  float oy = (v.y-mean)*rstd*gv.y + bv.y;
  float oz = (v.z-mean)*rstd*gv.z + bv.z;
  float ow = (v.w-mean)*rstd*gv.w + bv.w;
  unsigned q0 = (unsigned)f2bf(ox) | ((unsigned)f2bf(oy) << 16);
  unsigned q1 = (unsigned)f2bf(oz) | ((unsigned)f2bf(ow) << 16);
  uint2 pk = {q0, q1};
  *(uint2*)&y[r*1024 + t*4] = pk;
}

// ---------------- patch extraction -> bf16: x (B,V,256,512) -> xp (B,V,512,256) -------
__global__ void xp_extract(const float* __restrict__ x, unsigned short* __restrict__ xp)
{
  int idx = blockIdx.x * 256 + threadIdx.x;          // 262144 groups of 4
  int e4 = idx & 63;
  int lt = (idx >> 6) & 511;
  int zz = idx >> 15;
  int e  = e4 << 2;
  int py = e >> 4, px0 = e & 15;
  int hy = lt >> 5, wx = lt & 31;
  float4 v = *(const float4*)&x[((long)zz*256 + hy*16 + py)*512 + wx*16 + px0];
  unsigned q0 = (unsigned)f2bf(v.x) | ((unsigned)f2bf(v.y) << 16);
  unsigned q1 = (unsigned)f2bf(v.z) | ((unsigned)f2bf(v.w) << 16);
  uint2 pk = {q0, q1};
  ((uint2*)xp)[idx] = pk;
}

__global__ void pb2_combine(const float* __restrict__ pb, const float* __restrict__ ve,
                            float* __restrict__ out)
{
  int i = blockIdx.x * 256 + threadIdx.x;            // 4096
  out[i] = pb[i] + ve[i];
}

__global__ void qproj(const float* __restrict__ vq, const float* __restrict__ wq,
                      float* __restrict__ q)
{
  int n = blockIdx.x * 64 + threadIdx.x;             // 1024
  float s = 0.f;
  for (int k = 0; k < 1024; ++k) s += vq[k] * wq[(long)k*1024 + n];
  q[n] = s;
}

// fold K-projection with query: wt[h][D] = sum_d agg_wk[D][h*64+d] * q[h*64+d]
__global__ void wk_fold(const float* __restrict__ wk, const float* __restrict__ qv,
                        float* __restrict__ wt)
{
  int i = blockIdx.x * 256 + threadIdx.x;            // 16384
  int h = i & 15, D = i >> 4;
  const float* wr = wk + (long)D*1024 + h*64;
  const float* qr = qv + h*64;
  float s = 0.f;
  #pragma unroll
  for (int d = 0; d < 64; ++d) s += wr[d]*qr[d];
  wt[h*1024 + D] = s;
}

// aggregate_variables attention with folded scores: one block per (l,h,b), 64 thr
__global__ __launch_bounds__(64)
void agg_attn2(const unsigned short* __restrict__ tok, const float* __restrict__ vb,
               const float* __restrict__ wt, unsigned short* __restrict__ out)
{
  int l = blockIdx.x, h = blockIdx.y, b = blockIdx.z, t = threadIdx.x;
  const float* wh = wt + h*1024;
  float sc[4];
  #pragma unroll
  for (int v = 0; v < 4; ++v){
    const unsigned short* tr = tok + ((((long)b*4 + v)*512 + l) << 10);
    float s = 0.f;
    #pragma unroll
    for (int j = 0; j < 16; ++j){
      int D = t + j*64;
      s += bf2f(tr[D]) * wh[D];
    }
    #pragma unroll
    for (int o = 32; o; o >>= 1) s += __shfl_xor(s, o);
    sc[v] = s * 0.125f;
  }
  float m = fmaxf(fmaxf(sc[0], sc[1]), fmaxf(sc[2], sc[3]));
  float e0 = __expf(sc[0]-m), e1 = __expf(sc[1]-m), e2 = __expf(sc[2]-m), e3 = __expf(sc[3]-m);
  float inv = 1.0f / (e0 + e1 + e2 + e3);
  long base = (((long)b*4)*512 + l)*1024 + h*64 + t;
  float o = e0*vb[base] + e1*vb[base + 512*1024] + e2*vb[base + 2*512*1024] + e3*vb[base + 3*512*1024];
  out[(((long)b*512 + l) << 10) + h*64 + t] = f2bf(o * inv);
}

// ---------------- flash-tile self-attention: 32 q-rows x 1 head per block -------------
__global__ __launch_bounds__(256)
void attn_v2(const float* __restrict__ qkv, unsigned short* __restrict__ out, int N)
{
  int h = blockIdx.y, b = blockIdx.z;
  int row0 = blockIdx.x * 32;
  int t = threadIdx.x;
  int r = t & 31, g = t >> 5;
  int c0 = g * 8;
  const float* base = qkv + (long)b * N * 3072;

  __shared__ float QsT[64][33];
  __shared__ float KV[64][68];
  __shared__ float Ps[32][65];
  __shared__ float red[32][9], red2[32][9];

  {
    const float* qp = base + (long)(row0 + r)*3072 + h*64 + c0;
    float4 a  = *(const float4*)qp;
    float4 bq = *(const float4*)(qp + 4);
    QsT[c0+0][r]=a.x;  QsT[c0+1][r]=a.y;  QsT[c0+2][r]=a.z;  QsT[c0+3][r]=a.w;
    QsT[c0+4][r]=bq.x; QsT[c0+5][r]=bq.y; QsT[c0+6][r]=bq.z; QsT[c0+7][r]=bq.w;
  }
  float m_r = -1e30f, l_r = 0.f;
  float O[8] = {0,0,0,0,0,0,0,0};
  int vc = t & 63, vd = (t >> 6) * 16;

  for (int j0 = 0; j0 < N; j0 += 64){
    __syncthreads();
    {
      const float* kp = base + (long)(j0 + vc)*3072 + 1024 + h*64 + vd;
      float4 k1 = *(const float4*)kp,     k2 = *(const float4*)(kp+4);
      float4 k3 = *(const float4*)(kp+8), k4 = *(const float4*)(kp+12);
      KV[vd+ 0][vc]=k1.x; KV[vd+ 1][vc]=k1.y; KV[vd+ 2][vc]=k1.z; KV[vd+ 3][vc]=k1.w;
      KV[vd+ 4][vc]=k2.x; KV[vd+ 5][vc]=k2.y; KV[vd+ 6][vc]=k2.z; KV[vd+ 7][vc]=k2.w;
      KV[vd+ 8][vc]=k3.x; KV[vd+ 9][vc]=k3.y; KV[vd+10][vc]=k3.z; KV[vd+11][vc]=k3.w;
      KV[vd+12][vc]=k4.x; KV[vd+13][vc]=k4.y; KV[vd+14][vc]=k4.z; KV[vd+15][vc]=k4.w;
    }
    __syncthreads();
    float s[8] = {0,0,0,0,0,0,0,0};
    #pragma unroll 16
    for (int d = 0; d < 64; ++d){
      float q = QsT[d][r];
      float4 k1 = *(const float4*)&KV[d][c0];
      float4 k2 = *(const float4*)&KV[d][c0+4];
      s[0] += q*k1.x; s[1] += q*k1.y; s[2] += q*k1.z; s[3] += q*k1.w;
      s[4] += q*k2.x; s[5] += q*k2.y; s[6] += q*k2.z; s[7] += q*k2.w;
    }
    float lm = -1e30f;
    #pragma unroll
    for (int i = 0; i < 8; ++i){ s[i] *= 0.125f; lm = fmaxf(lm, s[i]); }
    red[r][g] = lm;
    __syncthreads();
    float mc = red[r][0];
    #pragma unroll
    for (int gg = 1; gg < 8; ++gg) mc = fmaxf(mc, red[r][gg]);
    float m_new = fmaxf(m_r, mc);
    float alpha = __expf(m_r - m_new);
    float ls = 0.f;
    #pragma unroll
    for (int i = 0; i < 8; ++i){ float p = __expf(s[i]-m_new); Ps[r][c0+i] = p; ls += p; }
    red2[r][g] = ls;
    __syncthreads();
    float cs = 0.f;
    #pragma unroll
    for (int gg = 0; gg < 8; ++gg) cs += red2[r][gg];
    l_r = alpha*l_r + cs;
    m_r = m_new;
    #pragma unroll
    for (int i = 0; i < 8; ++i) O[i] *= alpha;
    {
      const float* vp = base + (long)(j0 + vc)*3072 + 2048 + h*64 + vd;
      float4 v1 = *(const float4*)vp,     v2 = *(const float4*)(vp+4);
      float4 v3 = *(const float4*)(vp+8), v4 = *(const float4*)(vp+12);
      *(float4*)&KV[vc][vd]    = v1;
      *(float4*)&KV[vc][vd+4]  = v2;
      *(float4*)&KV[vc][vd+8]  = v3;
      *(float4*)&KV[vc][vd+12] = v4;
    }
    __syncthreads();
    #pragma unroll 16
    for (int j = 0; j < 64; ++j){
      float p = Ps[r][j];
      float4 v1 = *(const float4*)&KV[j][c0];
      float4 v2 = *(const float4*)&KV[j][c0+4];
      O[0] += p*v1.x; O[1] += p*v1.y; O[2] += p*v1.z; O[3] += p*v1.w;
      O[4] += p*v2.x; O[5] += p*v2.y; O[6] += p*v2.z; O[7] += p*v2.w;
    }
  }
  float inv = 1.0f / l_r;
  unsigned q0 = (unsigned)f2bf(O[0]*inv) | ((unsigned)f2bf(O[1]*inv) << 16);
  unsigned q1 = (unsigned)f2bf(O[2]*inv) | ((unsigned)f2bf(O[3]*inv) << 16);
  unsigned q2 = (unsigned)f2bf(O[4]*inv) | ((unsigned)f2bf(O[5]*inv) << 16);
  unsigned q3 = (unsigned)f2bf(O[6]*inv) | ((unsigned)f2bf(O[7]*inv) << 16);
  uint4 pk = {q0, q1, q2, q3};
  *(uint4*)&out[((long)(b*N + row0 + r))*1024 + h*64 + c0] = pk;
}

// gather / scatter 128 hard tokens per batch (fp32 stream)
__global__ __launch_bounds__(256)
void gather_rows(const float* __restrict__ src, const int* __restrict__ idx,
                 float* __restrict__ dst)
{
  int r = blockIdx.x;
  int b = r >> 7, i = r & 127;
  int s = idx[b*128 + i];
  ((float4*)(dst + (long)r*1024))[threadIdx.x] =
      ((const float4*)(src + ((long)b*512 + s)*1024))[threadIdx.x];
}
__global__ __launch_bounds__(256)
void scatter_rows(const float* __restrict__ src, const int* __restrict__ idx,
                  float* __restrict__ dst)
{
  int r = blockIdx.x;
  int b = r >> 7, i = r & 127;
  int s = idx[b*128 + i];
  ((float4*)(dst + ((long)b*512 + s)*1024))[threadIdx.x] =
      ((const float4*)(src + (long)r*1024))[threadIdx.x];
}

// conv1 v2: x (B,4,256,512) -> gelu(conv3x3) -> channels-last (B,256,512,64)
// One thread per pixel, all 64 output channels; weights via uniform scalar loads.
__global__ __launch_bounds__(256)
void conv1_v2(const float* __restrict__ x, const float* __restrict__ w,
              const float* __restrict__ bi, float* __restrict__ out)
{
  int id = blockIdx.x*256 + threadIdx.x;   // 262144 pixels
  int px = id & 511, py = (id >> 9) & 255, bb = id >> 17;
  float in[4][9];
  #pragma unroll
  for (int ci = 0; ci < 4; ++ci){
    const float* xc = x + ((long)(bb*4 + ci)*256)*512;
    #pragma unroll
    for (int ky = 0; ky < 3; ++ky){
      int yy = py + ky - 1;
      #pragma unroll
      for (int kx = 0; kx < 3; ++kx){
        int xx = px + kx - 1;
        bool ok = ((unsigned)yy < 256u) && ((unsigned)xx < 512u);
        in[ci][ky*3+kx] = ok ? xc[yy*512 + xx] : 0.f;
      }
    }
  }
  float* op = out + (long)id*64;
  #pragma unroll 4
  for (int cog = 0; cog < 16; ++cog){
    float4 a;
    #pragma unroll
    for (int u = 0; u < 4; ++u){
      int co = cog*4 + u;
      float s = bi[co];
      #pragma unroll
      for (int ci = 0; ci < 4; ++ci){
        const float* wc = w + (co*4 + ci)*9;
        #pragma unroll
        for (int k = 0; k < 9; ++k) s += in[ci][k]*wc[k];
      }
      ((float*)&a)[u] = gelu_f(s);
    }
    *(float4*)(op + cog*4) = a;
  }
}

// conv2 v2 (pixel_shuffle fused): r1 channels-last (B,256,512,64) -> r2 (B,1024,2048)
// LDS-tiled: 64x16 output tile, 18x6 low-res cells x 64 ch staged, stride-68 pad.
__global__ __launch_bounds__(256)
void conv2_v2(const float* __restrict__ r1, const float* __restrict__ w,
              const float* __restrict__ bi, float* __restrict__ out)
{
  __shared__ float cbuf[108*68];   // 29.4 KB
  int X0 = blockIdx.x*64, Y0 = blockIdx.y*16, bb = blockIdx.z;
  int cx0 = (X0 >> 2) - 1, cy0 = (Y0 >> 2) - 1;
  int t = threadIdx.x;
  const float* rb = r1 + (long)bb*256*512*64;
  for (int i4 = t; i4 < 1728; i4 += 256){
    int cell = i4 >> 4, ch4 = (i4 & 15) << 2;
    int cy = cy0 + cell/18, cx = cx0 + cell%18;
    float4 v = {0.f, 0.f, 0.f, 0.f};
    if ((unsigned)cy < 256u && (unsigned)cx < 512u)
      v = *(const float4*)&rb[(((long)cy*512 + cx) << 6) + ch4];
    *(float4*)&cbuf[cell*68 + ch4] = v;
  }
  float wv[36];
  #pragma unroll
  for (int k = 0; k < 36; ++k) wv[k] = w[k];
  float bias = bi[0];
  __syncthreads();
  int lx = t & 63, tq = t >> 6;
  int X = X0 + lx;
  #pragma unroll
  for (int j = 0; j < 4; ++j){
    int Y = Y0 + tq*4 + j;
    float s = bias;
    #pragma unroll
    for (int ky = 0; ky < 3; ++ky){
      int yy = Y + ky - 1;
      if ((unsigned)yy >= 1024u) continue;
      int ly = (yy >> 2) - cy0, phy = (yy & 3) << 2;
      #pragma unroll
      for (int kx = 0; kx < 3; ++kx){
        int xx = X + kx - 1;
        if ((unsigned)xx >= 2048u) continue;
        int lxc = (xx >> 2) - cx0;
        const float* cp = &cbuf[(ly*18 + lxc)*68 + phy + (xx & 3)];
        s += cp[0]*wv[ky*3+kx] + cp[16]*wv[9+ky*3+kx]
           + cp[32]*wv[18+ky*3+kx] + cp[48]*wv[27+ky*3+kx];
      }
    }
    out[(((long)bb*1024 + Y) << 11) + X] = s;
  }
}

// fused: ysum (unpatchify remap + r2) staged in LDS tile, then final 3x3 conv -> d_out
__global__ __launch_bounds__(256)
void cout_fused(const float* __restrict__ pred, const float* __restrict__ r2,
                const float* __restrict__ w, const float* __restrict__ bi,
                float* __restrict__ out)
{
  __shared__ float tb[18*66];
  int X0 = blockIdx.x*64, Y0 = blockIdx.y*16, bb = blockIdx.z;
  int t = threadIdx.x;
  for (int i = t; i < 1188; i += 256){
    int ly = i/66, lx = i%66;
    int Y = Y0 + ly - 1, X = X0 + lx - 1;
    float v = 0.f;
    if ((unsigned)Y < 1024u && (unsigned)X < 2048u){
      int i2 = Y >> 4, p = Y & 15, j2 = X >> 4, q = X & 15;
      int l = i2*8 + (j2 >> 4);
      int e = ((j2 & 15) << 8) + (p << 4) + q;
      v = pred[(((long)bb*512 + l) << 12) + e] + r2[(((long)bb*1024 + Y) << 11) + X];
    }
    tb[i] = v;
  }
  float w0=w[0], w1=w[1], w2=w[2], w3=w[3], w4=w[4], w5=w[5], w6=w[6], w7=w[7], w8=w[8];
  float bias = bi[0];
  __syncthreads();
  int lx = t & 63, tq = t >> 6;
  #pragma unroll
  for (int j = 0; j < 4; ++j){
    int ry = tq*4 + j;
    const float* c = &tb[ry*66 + lx];
    float s = bias + c[0]*w0 + c[1]*w1 + c[2]*w2
            + c[66]*w3 + c[67]*w4 + c[68]*w5
            + c[132]*w6 + c[133]*w7 + c[134]*w8;
    out[(((long)bb*1024 + Y0 + ry) << 11) + X0 + lx] = s;
  }
}

// ---------------------------------------------------------------------------------------
static inline void wtrans_go(hipStream_t st, const float* W, unsigned short* Wt,
                             int K, int N, int batch)
{
  dim3 g(N/32, K/32, batch);
  wtrans<<<g, 256, 0, st>>>(W, Wt, K, N, (long)K*N);
}

static inline void gemm_go(hipStream_t st, int TM, const unsigned short* A,
                           const unsigned short* Wt,
                           const float* bias, const float* res, float* Cf, unsigned short* Cb,
                           int M, int N, int K, int batches,
                           long sA, long sW, long sBias, long sRes, long sC,
                           int wmod, int act)
{
  dim3 g(N/128, M/TM, batches);
  if (TM == 128)
    gemm_bt<128><<<g, 256, 0, st>>>(A, Wt, bias, res, Cf, Cb, M, N, K, N,
                                    sA, sW, sBias, sRes, sC, wmod, act);
  else
    gemm_bt<64><<<g, 256, 0, st>>>(A, Wt, bias, res, Cf, Cb, M, N, K, N,
                                   sA, sW, sBias, sRes, sC, wmod, act);
}

extern "C" void kernel_launch(void* const* d_in, const int* in_sizes, int n_in,
                              void* d_out, int out_size, void* d_ws, size_t ws_size,
                              hipStream_t stream)
{
  const float* x         = (const float*)d_in[0];
  const int*   hard_idx  = (const int*)  d_in[1];
  const float* patch_w   = (const float*)d_in[2];
  const float* patch_b   = (const float*)d_in[3];
  const float* var_embed = (const float*)d_in[4];
  const float* var_query = (const float*)d_in[5];
  const float* agg_wq    = (const float*)d_in[6];
  const float* agg_wk    = (const float*)d_in[7];
  const float* agg_wv    = (const float*)d_in[8];
  const float* agg_wo    = (const float*)d_in[9];
  const float* agg_bo    = (const float*)d_in[10];
  const float* pos_embed = (const float*)d_in[11];
  const float* ln1_w     = (const float*)d_in[12];
  const float* ln1_b     = (const float*)d_in[13];
  const float* qkv_w     = (const float*)d_in[14];
  const float* qkv_b     = (const float*)d_in[15];
  const float* aproj_w   = (const float*)d_in[16];
  const float* aproj_b   = (const float*)d_in[17];
  const float* ln2_w     = (const float*)d_in[18];
  const float* ln2_b     = (const float*)d_in[19];
  const float* fc1_w     = (const float*)d_in[20];
  const float* fc1_b     = (const float*)d_in[21];
  const float* fc2_w     = (const float*)d_in[22];
  const float* fc2_b     = (const float*)d_in[23];
  const float* norm_w    = (const float*)d_in[24];
  const float* norm_b    = (const float*)d_in[25];
  const float* head_w    = (const float*)d_in[26];
  const float* head_b    = (const float*)d_in[27];
  const float* head_out_w= (const float*)d_in[28];
  const float* head_out_b= (const float*)d_in[29];
  const float* p2c1_w    = (const float*)d_in[30];
  const float* p2c1_b    = (const float*)d_in[31];
  const float* p2c2_w    = (const float*)d_in[32];
  const float* p2c2_b    = (const float*)d_in[33];
  const float* cout_w    = (const float*)d_in[34];
  const float* cout_b    = (const float*)d_in[35];

  float* ws = (float*)d_ws;
  float* xt   = ws;               // 1U fp32 stream (B,512,1024)
  float* r2   = ws + 1*UNIT;      // 4U
  float* qkvb = ws + 5*UNIT;      // 3U fp32 qkv
  float* pred = ws + 8*UNIT;      // 4U (phase3+)
  float* vb   = ws + 12*UNIT;     // 4U (phase1)
  float* rbig = ws + 8*UNIT;      // 16U channels-last conv1 out (phase0 only, 8..24U)
  unsigned short* b16 = (unsigned short*)(ws + 16*UNIT);   // 16M ushorts (16..24U)
  unsigned short* hn_bf    = b16;                // 1M
  unsigned short* ao_bf    = b16 + 1*UNIT;       // 1M
  unsigned short* ff_bf    = b16 + 2*UNIT;       // 4M
  unsigned short* xp_bf    = b16 + 6*UNIT;       // 1M
  unsigned short* tok_bf   = b16 + 7*UNIT;       // 4M
  unsigned short* aggin_bf = b16 + 11*UNIT;      // 1M
  unsigned short* wt_bf    = b16 + 12*UNIT;      // 4M (rotating transposed-weight slot)
  float* tail = ws + 24*UNIT;
  float* pb2  = tail;             // 4096
  float* qv   = tail + 4096;      // 1024
  float* wtl  = tail + 5120;      // 16384 (folded K-weights [16][1024])
  float* hbuf = tail + 21504;     // 0.25U (B,128,1024)

  // ---- Phase 0: residual conv path -> r2 ----
  conv1_v2<<<1024, 256, 0, stream>>>(x, p2c1_w, p2c1_b, rbig);
  conv2_v2<<<dim3(32, 64, 2), 256, 0, stream>>>(rbig, p2c2_w, p2c2_b, r2);

  // ---- Phase 1: patch embed + aggregate variables -> xt ----
  pb2_combine<<<16, 256, 0, stream>>>(patch_b, var_embed, pb2);
  xp_extract<<<1024, 256, 0, stream>>>(x, xp_bf);
  wtrans_go(stream, patch_w, wt_bf, 256, 1024, 4);
  gemm_go(stream, 128, xp_bf, wt_bf, pb2, nullptr, nullptr, tok_bf,
          512, 1024, 256, 8, 512L*256, 256L*1024, 1024, 0, 512L*1024, 4, 0);
  qproj<<<16, 64, 0, stream>>>(var_query, agg_wq, qv);
  wk_fold<<<64, 256, 0, stream>>>(agg_wk, qv, wtl);
  wtrans_go(stream, agg_wv, wt_bf, 1024, 1024, 1);
  gemm_go(stream, 128, tok_bf, wt_bf, nullptr, nullptr, vb, nullptr,
          512, 1024, 1024, 8, 512L*1024, 0, 0, 0, 512L*1024, 1, 0);
  agg_attn2<<<dim3(512, 16, 2), 64, 0, stream>>>(tok_bf, vb, wtl, aggin_bf);
  wtrans_go(stream, agg_wo, wt_bf, 1024, 1024, 1);
  gemm_go(stream, 64, aggin_bf, wt_bf, agg_bo, pos_embed, xt, nullptr,
          512, 1024, 1024, 2, 512L*1024, 0, 0, 0, 512L*1024, 1, 0);

  // ---- Phase 2: transformer blocks ----
  auto run_block = [&](float* cur, int Nt, int d){
    int rows = 2 * Nt;
    int TMbig = (rows >= 1024) ? 128 : 64;
    ln_bf<<<rows, 256, 0, stream>>>(cur, ln1_w + d*1024, ln1_b + d*1024, hn_bf);
    wtrans_go(stream, qkv_w + (long)d*1024*3072, wt_bf, 1024, 3072, 1);
    gemm_go(stream, TMbig, hn_bf, wt_bf, qkv_b + d*3072, nullptr, qkvb, nullptr,
            rows, 3072, 1024, 1, 0, 0, 0, 0, 0, 1, 0);
    attn_v2<<<dim3(Nt/32, 16, 2), 256, 0, stream>>>(qkvb, ao_bf, Nt);
    wtrans_go(stream, aproj_w + (long)d*1024*1024, wt_bf, 1024, 1024, 1);
    gemm_go(stream, 64, ao_bf, wt_bf, aproj_b + d*1024, cur, cur, nullptr,
            rows, 1024, 1024, 1, 0, 0, 0, 0, 0, 1, 0);
    ln_bf<<<rows, 256, 0, stream>>>(cur, ln2_w + d*1024, ln2_b + d*1024, hn_bf);
    wtrans_go(stream, fc1_w + (long)d*1024*4096, wt_bf, 1024, 4096, 1);
    gemm_go(stream, TMbig, hn_bf, wt_bf, fc1_b + d*4096, nullptr, nullptr, ff_bf,
            rows, 4096, 1024, 1, 0, 0, 0, 0, 0, 1, 1);
    wtrans_go(stream, fc2_w + (long)d*4096*1024, wt_bf, 4096, 1024, 1);
    gemm_go(stream, 64, ff_bf, wt_bf, fc2_b + d*1024, cur, cur, nullptr,
            rows, 1024, 4096, 1, 0, 0, 0, 0, 0, 1, 0);
  };

  run_block(xt, 512, 0);
  run_block(xt, 512, 1);
  gather_rows<<<256, 256, 0, stream>>>(xt, hard_idx, hbuf);
  run_block(hbuf, 128, 2);
  run_block(hbuf, 128, 3);
  run_block(hbuf, 128, 4);
  scatter_rows<<<256, 256, 0, stream>>>(hbuf, hard_idx, xt);
  run_block(xt, 512, 5);

  // ---- Phase 3: final LN + head ----
  ln_bf<<<1024, 256, 0, stream>>>(xt, norm_w, norm_b, hn_bf);
  wtrans_go(stream, head_w, wt_bf, 1024, 1024, 1);
  gemm_go(stream, 64, hn_bf, wt_bf, head_b, nullptr, nullptr, ao_bf,
          1024, 1024, 1024, 1, 0, 0, 0, 0, 0, 1, 1);
  wtrans_go(stream, head_w + 1024L*1024, wt_bf, 1024, 1024, 1);
  gemm_go(stream, 64, ao_bf, wt_bf, head_b + 1024, nullptr, nullptr, hn_bf,
          1024, 1024, 1024, 1, 0, 0, 0, 0, 0, 1, 1);
  wtrans_go(stream, head_out_w, wt_bf, 1024, 4096, 1);
  gemm_go(stream, 128, hn_bf, wt_bf, head_out_b, nullptr, pred, nullptr,
          1024, 4096, 1024, 1, 0, 0, 0, 0, 0, 1, 0);

  // ---- Phase 4: fused unpatchify + residual + final conv ----
  cout_fused<<<dim3(32, 64, 2), 256, 0, stream>>>(pred, r2, cout_w, cout_b, (float*)d_out);
}

// Round 5
// 1597.925 us; speedup vs baseline: 3.8615x; 1.2698x over previous
//
#include <hip/hip_runtime.h>
#include <math.h>

// Res_Slim_ViT_Adaptive — r5: coalesced bf16 conv1, split-K GEMMs + epilogue reduce,
// merged wtrans groups.
// Shapes: P=16 D=1024 NH=16 HD=64 MAG=4 B=2 V=4 H=256 W=512 L=512 KEEP=128 DEPTH=6

#define UNIT 1048576L   // 1M elements

typedef __attribute__((ext_vector_type(8))) short short8;
typedef __attribute__((ext_vector_type(4))) float f32x4;

#define GLDS(gp, lp) __builtin_amdgcn_global_load_lds( \
    (const __attribute__((address_space(1))) void*)(gp), \
    (__attribute__((address_space(3))) void*)(lp), 16, 0, 0)

__device__ __forceinline__ float gelu_f(float v){
  return 0.5f*v*(1.0f + erff(v*0.70710678118654752440f));
}

__device__ __forceinline__ unsigned short f2bf(float f){
  union { float f; unsigned u; } a; a.f = f;
  unsigned r = a.u + 0x7fffu + ((a.u >> 16) & 1u);
  return (unsigned short)(r >> 16);
}
__device__ __forceinline__ float bf2f(unsigned short u){
  union { unsigned u; float f; } a; a.u = (unsigned)u << 16;
  return a.f;
}

// =============== multi-job transpose-convert: W fp32 [K][N] -> Wt bf16 [N][K] =========
struct WJobs {
  const float* W[4];
  unsigned short* T[4];
  int K[4], N[4];
  int start[4];    // block-range starts; unused jobs start = 0x7fffffff
};

__global__ __launch_bounds__(256)
void wtrans_multi(WJobs J)
{
  __shared__ float tile[32][33];
  int bx = blockIdx.x;
  int j = 0;
  #pragma unroll
  for (int i = 1; i < 4; ++i) if (bx >= J.start[i]) j = i;
  int local = bx - J.start[j];
  int K = J.K[j], N = J.N[j];
  int nx = N >> 5, tpb = (K >> 5) * nx;
  int bz = local / tpb, rem = local % tpb;
  int k0 = (rem / nx) * 32, n0 = (rem % nx) * 32;
  const float* Wp = J.W[j] + (long)bz * K * N;
  unsigned short* Wo = J.T[j] + (long)bz * K * N;
  int tx = threadIdx.x & 31, ty = threadIdx.x >> 5;   // 32 x 8
  #pragma unroll
  for (int i = 0; i < 4; ++i)
    tile[ty*4+i][tx] = Wp[(long)(k0 + ty*4 + i)*N + n0 + tx];
  __syncthreads();
  #pragma unroll
  for (int i = 0; i < 4; ++i){
    int n = ty*4 + i;
    Wo[(long)(n0 + n)*K + k0 + tx] = f2bf(tile[tx][n]);
  }
}

// =============== bf16 MFMA GEMM with optional split-K partial output ==================
// A: bf16 [M][K]; Wt: bf16 [N][K]. Tile TM x 128, BK=32, 256 threads.
template<int TM>
__global__ __launch_bounds__(256)
void gemm_bt(const unsigned short* __restrict__ A, const unsigned short* __restrict__ Wt,
             const float* __restrict__ bias, const float* __restrict__ res,
             float* __restrict__ Cf, unsigned short* __restrict__ Cb,
             float* __restrict__ Cp, long MN, int splits,
             int M, int N, int K, int ldc,
             long sA, long sW, long sBias, long sRes, long sC,
             int wmod, int act)
{
  constexpr int NJ = (TM == 128) ? 4 : 2;
  int bz0 = blockIdx.z;
  int sp = bz0 % splits, bz = bz0 / splits;
  A += (long)bz * sA;
  int wb = bz % wmod;
  Wt += (long)wb * sW;
  const float* bptr = bias ? bias + (long)wb * sBias : nullptr;
  const float* rptr = res  ? res  + (long)bz * sRes : nullptr;
  if (Cf) Cf += (long)bz * sC;
  if (Cb) Cb += (long)bz * sC;

  __shared__ __align__(16) unsigned short As[TM*32];
  __shared__ __align__(16) unsigned short Bs[128*32];

  int t = threadIdx.x;
  int wave = t >> 6, lane = t & 63;
  int ln = lane & 15, kg = lane >> 4;
  int wm, wn;
  if (TM == 128){ wm = (wave & 1) * 64; wn = (wave >> 1) * 64; }
  else          { wm = 0;               wn = wave * 32; }
  int row0 = blockIdx.y * TM, col0 = blockIdx.x * 128;

  f32x4 acc[4][NJ];
  f32x4 z = {0.f, 0.f, 0.f, 0.f};
  #pragma unroll
  for (int i = 0; i < 4; ++i)
    #pragma unroll
    for (int j = 0; j < NJ; ++j) acc[i][j] = z;

  int sm = t >> 2;          // 0..63
  int sk = (t & 3) * 8;     // halfword offset
  unsigned short* AsB = As + wave*512;
  unsigned short* BsB = Bs + wave*512;

  int kpb = K / splits;
  int kbeg = sp * kpb, kend = kbeg + kpb;
  for (int k0 = kbeg; k0 < kend; k0 += 32){
    if (TM == 128){
      GLDS(&A[(long)(row0 + sm)*K + k0 + sk],      AsB);
      GLDS(&A[(long)(row0 + 64 + sm)*K + k0 + sk], AsB + 2048);
    } else {
      GLDS(&A[(long)(row0 + sm)*K + k0 + sk],      AsB);
    }
    GLDS(&Wt[(long)(col0 + sm)*K + k0 + sk],      BsB);
    GLDS(&Wt[(long)(col0 + 64 + sm)*K + k0 + sk], BsB + 2048);
    __syncthreads();
    short8 af[4], bfg[NJ];
    #pragma unroll
    for (int i = 0; i < 4; ++i)  af[i]  = *(const short8*)&As[(wm + i*16 + ln)*32 + kg*8];
    #pragma unroll
    for (int j = 0; j < NJ; ++j) bfg[j] = *(const short8*)&Bs[(wn + j*16 + ln)*32 + kg*8];
    #pragma unroll
    for (int i = 0; i < 4; ++i)
      #pragma unroll
      for (int j = 0; j < NJ; ++j)
        acc[i][j] = __builtin_amdgcn_mfma_f32_16x16x32_bf16(af[i], bfg[j], acc[i][j], 0, 0, 0);
    __syncthreads();
  }

  // C/D layout: col = lane&15, row = (lane>>4)*4 + reg
  if (Cp){
    long nbat = gridDim.z / splits;
    float* P = Cp + ((long)sp*nbat + bz)*MN;
    #pragma unroll
    for (int i = 0; i < 4; ++i){
      int rbase = row0 + wm + i*16 + kg*4;
      #pragma unroll
      for (int j = 0; j < NJ; ++j){
        int c = col0 + wn + j*16 + ln;
        #pragma unroll
        for (int rr2 = 0; rr2 < 4; ++rr2)
          P[(long)(rbase + rr2)*ldc + c] = acc[i][j][rr2];
      }
    }
    return;
  }
  #pragma unroll
  for (int i = 0; i < 4; ++i){
    int rbase = row0 + wm + i*16 + kg*4;
    #pragma unroll
    for (int j = 0; j < NJ; ++j){
      int c = col0 + wn + j*16 + ln;
      float bv = bptr ? bptr[c] : 0.f;
      #pragma unroll
      for (int rr2 = 0; rr2 < 4; ++rr2){
        int rrow = rbase + rr2;
        float v = acc[i][j][rr2] + bv;
        if (rptr) v += rptr[(long)rrow*ldc + c];
        if (act == 1) v = gelu_f(v);
        if (Cf) Cf[(long)rrow*ldc + c] = v;
        if (Cb) Cb[(long)rrow*ldc + c] = f2bf(v);
      }
    }
  }
}

// ---------------- split-K epilogue reduce: sum partials + bias + res + act ------------
__global__ __launch_bounds__(256)
void reduce_ep(const float* __restrict__ Cp, int splits, int nbat, long MN, int N,
               const float* __restrict__ bias, const float* __restrict__ res, long sRes,
               float* __restrict__ Cf, unsigned short* __restrict__ Cb, long sC, int act)
{
  long e4 = (long)blockIdx.x*256 + threadIdx.x;
  if (e4 >= (long)nbat*MN/4) return;
  long e = e4 * 4;
  int b = (int)(e / MN); long r = e % MN; int col = (int)(r % N);
  float4 s = *(const float4*)&Cp[(long)b*MN + r];
  for (int sp = 1; sp < splits; ++sp){
    float4 p = *(const float4*)&Cp[((long)sp*nbat + b)*MN + r];
    s.x += p.x; s.y += p.y; s.z += p.z; s.w += p.w;
  }
  if (bias){
    float4 bv = *(const float4*)&bias[col];
    s.x += bv.x; s.y += bv.y; s.z += bv.z; s.w += bv.w;
  }
  if (res){
    float4 rv = *(const float4*)&res[(long)b*sRes + r];
    s.x += rv.x; s.y += rv.y; s.z += rv.z; s.w += rv.w;
  }
  if (act == 1){
    s.x = gelu_f(s.x); s.y = gelu_f(s.y); s.z = gelu_f(s.z); s.w = gelu_f(s.w);
  }
  if (Cf) *(float4*)&Cf[(long)b*sC + r] = s;
  if (Cb){
    unsigned q0 = (unsigned)f2bf(s.x) | ((unsigned)f2bf(s.y) << 16);
    unsigned q1 = (unsigned)f2bf(s.z) | ((unsigned)f2bf(s.w) << 16);
    uint2 pk = {q0, q1};
    *(uint2*)&Cb[(long)b*sC + r] = pk;
  }
}

// ---------------- LayerNorm over D=1024 -> bf16 out, one row per block ----------------
__global__ __launch_bounds__(256)
void ln_bf(const float* __restrict__ x, const float* __restrict__ g,
           const float* __restrict__ b, unsigned short* __restrict__ y)
{
  long r = blockIdx.x;
  int t = threadIdx.x;
  float4 v = ((const float4*)(x + r*1024))[t];
  float s  = v.x + v.y + v.z + v.w;
  float ss = v.x*v.x + v.y*v.y + v.z*v.z + v.w*v.w;
  #pragma unroll
  for (int o = 32; o; o >>= 1){ s += __shfl_xor(s, o); ss += __shfl_xor(ss, o); }
  __shared__ float sa[4], sb[4];
  int w = t >> 6, lane = t & 63;
  if (!lane){ sa[w] = s; sb[w] = ss; }
  __syncthreads();
  s  = sa[0] + sa[1] + sa[2] + sa[3];
  ss = sb[0] + sb[1] + sb[2] + sb[3];
  float mean = s * (1.0f/1024.0f);
  float var  = ss * (1.0f/1024.0f) - mean*mean;
  float rstd = rsqrtf(var + 1e-5f);
  float4 gv = ((const float4*)g)[t];
  float4 bv = ((const float4*)b)[t];
  float ox = (v.x-mean)*rstd*gv.x + bv.x;
  float oy = (v.y-mean)*rstd*gv.y + bv.y;
  float oz = (v.z-mean)*rstd*gv.z + bv.z;
  float ow = (v.w-mean)*rstd*gv.w + bv.w;
  unsigned q0 = (unsigned)f2bf(ox) | ((unsigned)f2bf(oy) << 16);
  unsigned q1 = (unsigned)f2bf(oz) | ((unsigned)f2bf(ow) << 16);
  uint2 pk = {q0, q1};
  *(uint2*)&y[r*1024 + t*4] = pk;
}

// ---------------- patch extraction -> bf16 --------------------------------------------
__global__ void xp_extract(const float* __restrict__ x, unsigned short* __restrict__ xp)
{
  int idx = blockIdx.x * 256 + threadIdx.x;
  int e4 = idx & 63;
  int lt = (idx >> 6) & 511;
  int zz = idx >> 15;
  int e  = e4 << 2;
  int py = e >> 4, px0 = e & 15;
  int hy = lt >> 5, wx = lt & 31;
  float4 v = *(const float4*)&x[((long)zz*256 + hy*16 + py)*512 + wx*16 + px0];
  unsigned q0 = (unsigned)f2bf(v.x) | ((unsigned)f2bf(v.y) << 16);
  unsigned q1 = (unsigned)f2bf(v.z) | ((unsigned)f2bf(v.w) << 16);
  uint2 pk = {q0, q1};
  ((uint2*)xp)[idx] = pk;
}

__global__ void pb2_combine(const float* __restrict__ pb, const float* __restrict__ ve,
                            float* __restrict__ out)
{
  int i = blockIdx.x * 256 + threadIdx.x;
  out[i] = pb[i] + ve[i];
}

__global__ void qproj(const float* __restrict__ vq, const float* __restrict__ wq,
                      float* __restrict__ q)
{
  int n = blockIdx.x * 64 + threadIdx.x;
  float s = 0.f;
  for (int k = 0; k < 1024; ++k) s += vq[k] * wq[(long)k*1024 + n];
  q[n] = s;
}

__global__ void wk_fold(const float* __restrict__ wk, const float* __restrict__ qv,
                        float* __restrict__ wt)
{
  int i = blockIdx.x * 256 + threadIdx.x;
  int h = i & 15, D = i >> 4;
  const float* wr = wk + (long)D*1024 + h*64;
  const float* qr = qv + h*64;
  float s = 0.f;
  #pragma unroll
  for (int d = 0; d < 64; ++d) s += wr[d]*qr[d];
  wt[h*1024 + D] = s;
}

__global__ __launch_bounds__(64)
void agg_attn2(const unsigned short* __restrict__ tok, const float* __restrict__ vb,
               const float* __restrict__ wt, unsigned short* __restrict__ out)
{
  int l = blockIdx.x, h = blockIdx.y, b = blockIdx.z, t = threadIdx.x;
  const float* wh = wt + h*1024;
  float sc[4];
  #pragma unroll
  for (int v = 0; v < 4; ++v){
    const unsigned short* tr = tok + ((((long)b*4 + v)*512 + l) << 10);
    float s = 0.f;
    #pragma unroll
    for (int j = 0; j < 16; ++j){
      int D = t + j*64;
      s += bf2f(tr[D]) * wh[D];
    }
    #pragma unroll
    for (int o = 32; o; o >>= 1) s += __shfl_xor(s, o);
    sc[v] = s * 0.125f;
  }
  float m = fmaxf(fmaxf(sc[0], sc[1]), fmaxf(sc[2], sc[3]));
  float e0 = __expf(sc[0]-m), e1 = __expf(sc[1]-m), e2 = __expf(sc[2]-m), e3 = __expf(sc[3]-m);
  float inv = 1.0f / (e0 + e1 + e2 + e3);
  long base = (((long)b*4)*512 + l)*1024 + h*64 + t;
  float o = e0*vb[base] + e1*vb[base + 512*1024] + e2*vb[base + 2*512*1024] + e3*vb[base + 3*512*1024];
  out[(((long)b*512 + l) << 10) + h*64 + t] = f2bf(o * inv);
}

// ---------------- flash-tile self-attention -------------------------------------------
__global__ __launch_bounds__(256)
void attn_v2(const float* __restrict__ qkv, unsigned short* __restrict__ out, int N)
{
  int h = blockIdx.y, b = blockIdx.z;
  int row0 = blockIdx.x * 32;
  int t = threadIdx.x;
  int r = t & 31, g = t >> 5;
  int c0 = g * 8;
  const float* base = qkv + (long)b * N * 3072;

  __shared__ float QsT[64][33];
  __shared__ float KV[64][68];
  __shared__ float Ps[32][65];
  __shared__ float red[32][9], red2[32][9];

  {
    const float* qp = base + (long)(row0 + r)*3072 + h*64 + c0;
    float4 a  = *(const float4*)qp;
    float4 bq = *(const float4*)(qp + 4);
    QsT[c0+0][r]=a.x;  QsT[c0+1][r]=a.y;  QsT[c0+2][r]=a.z;  QsT[c0+3][r]=a.w;
    QsT[c0+4][r]=bq.x; QsT[c0+5][r]=bq.y; QsT[c0+6][r]=bq.z; QsT[c0+7][r]=bq.w;
  }
  float m_r = -1e30f, l_r = 0.f;
  float O[8] = {0,0,0,0,0,0,0,0};
  int vc = t & 63, vd = (t >> 6) * 16;

  for (int j0 = 0; j0 < N; j0 += 64){
    __syncthreads();
    {
      const float* kp = base + (long)(j0 + vc)*3072 + 1024 + h*64 + vd;
      float4 k1 = *(const float4*)kp,     k2 = *(const float4*)(kp+4);
      float4 k3 = *(const float4*)(kp+8), k4 = *(const float4*)(kp+12);
      KV[vd+ 0][vc]=k1.x; KV[vd+ 1][vc]=k1.y; KV[vd+ 2][vc]=k1.z; KV[vd+ 3][vc]=k1.w;
      KV[vd+ 4][vc]=k2.x; KV[vd+ 5][vc]=k2.y; KV[vd+ 6][vc]=k2.z; KV[vd+ 7][vc]=k2.w;
      KV[vd+ 8][vc]=k3.x; KV[vd+ 9][vc]=k3.y; KV[vd+10][vc]=k3.z; KV[vd+11][vc]=k3.w;
      KV[vd+12][vc]=k4.x; KV[vd+13][vc]=k4.y; KV[vd+14][vc]=k4.z; KV[vd+15][vc]=k4.w;
    }
    __syncthreads();
    float s[8] = {0,0,0,0,0,0,0,0};
    #pragma unroll 16
    for (int d = 0; d < 64; ++d){
      float q = QsT[d][r];
      float4 k1 = *(const float4*)&KV[d][c0];
      float4 k2 = *(const float4*)&KV[d][c0+4];
      s[0] += q*k1.x; s[1] += q*k1.y; s[2] += q*k1.z; s[3] += q*k1.w;
      s[4] += q*k2.x; s[5] += q*k2.y; s[6] += q*k2.z; s[7] += q*k2.w;
    }
    float lm = -1e30f;
    #pragma unroll
    for (int i = 0; i < 8; ++i){ s[i] *= 0.125f; lm = fmaxf(lm, s[i]); }
    red[r][g] = lm;
    __syncthreads();
    float mc = red[r][0];
    #pragma unroll
    for (int gg = 1; gg < 8; ++gg) mc = fmaxf(mc, red[r][gg]);
    float m_new = fmaxf(m_r, mc);
    float alpha = __expf(m_r - m_new);
    float ls = 0.f;
    #pragma unroll
    for (int i = 0; i < 8; ++i){ float p = __expf(s[i]-m_new); Ps[r][c0+i] = p; ls += p; }
    red2[r][g] = ls;
    __syncthreads();
    float cs = 0.f;
    #pragma unroll
    for (int gg = 0; gg < 8; ++gg) cs += red2[r][gg];
    l_r = alpha*l_r + cs;
    m_r = m_new;
    #pragma unroll
    for (int i = 0; i < 8; ++i) O[i] *= alpha;
    {
      const float* vp = base + (long)(j0 + vc)*3072 + 2048 + h*64 + vd;
      float4 v1 = *(const float4*)vp,     v2 = *(const float4*)(vp+4);
      float4 v3 = *(const float4*)(vp+8), v4 = *(const float4*)(vp+12);
      *(float4*)&KV[vc][vd]    = v1;
      *(float4*)&KV[vc][vd+4]  = v2;
      *(float4*)&KV[vc][vd+8]  = v3;
      *(float4*)&KV[vc][vd+12] = v4;
    }
    __syncthreads();
    #pragma unroll 16
    for (int j = 0; j < 64; ++j){
      float p = Ps[r][j];
      float4 v1 = *(const float4*)&KV[j][c0];
      float4 v2 = *(const float4*)&KV[j][c0+4];
      O[0] += p*v1.x; O[1] += p*v1.y; O[2] += p*v1.z; O[3] += p*v1.w;
      O[4] += p*v2.x; O[5] += p*v2.y; O[6] += p*v2.z; O[7] += p*v2.w;
    }
  }
  float inv = 1.0f / l_r;
  unsigned q0 = (unsigned)f2bf(O[0]*inv) | ((unsigned)f2bf(O[1]*inv) << 16);
  unsigned q1 = (unsigned)f2bf(O[2]*inv) | ((unsigned)f2bf(O[3]*inv) << 16);
  unsigned q2 = (unsigned)f2bf(O[4]*inv) | ((unsigned)f2bf(O[5]*inv) << 16);
  unsigned q3 = (unsigned)f2bf(O[6]*inv) | ((unsigned)f2bf(O[7]*inv) << 16);
  uint4 pk = {q0, q1, q2, q3};
  *(uint4*)&out[((long)(b*N + row0 + r))*1024 + h*64 + c0] = pk;
}

// gather / scatter 128 hard tokens per batch (fp32 stream)
__global__ __launch_bounds__(256)
void gather_rows(const float* __restrict__ src, const int* __restrict__ idx,
                 float* __restrict__ dst)
{
  int r = blockIdx.x;
  int b = r >> 7, i = r & 127;
  int s = idx[b*128 + i];
  ((float4*)(dst + (long)r*1024))[threadIdx.x] =
      ((const float4*)(src + ((long)b*512 + s)*1024))[threadIdx.x];
}
__global__ __launch_bounds__(256)
void scatter_rows(const float* __restrict__ src, const int* __restrict__ idx,
                  float* __restrict__ dst)
{
  int r = blockIdx.x;
  int b = r >> 7, i = r & 127;
  int s = idx[b*128 + i];
  ((float4*)(dst + ((long)b*512 + s)*1024))[threadIdx.x] =
      ((const float4*)(src + (long)r*1024))[threadIdx.x];
}

// conv1 v3: x (B,4,256,512) -> gelu(conv3x3) -> channels-last bf16 (B,256,512,64)
// One thread per pixel; 64 channels accumulated in regs; one 128B line per thread.
__global__ __launch_bounds__(256)
void conv1_v3(const float* __restrict__ x, const float* __restrict__ w,
              const float* __restrict__ bi, unsigned short* __restrict__ out)
{
  int id = blockIdx.x*256 + threadIdx.x;   // 262144 pixels
  int px = id & 511, py = (id >> 9) & 255, bb = id >> 17;
  float in[4][9];
  #pragma unroll
  for (int ci = 0; ci < 4; ++ci){
    const float* xc = x + ((long)(bb*4 + ci)*256)*512;
    #pragma unroll
    for (int ky = 0; ky < 3; ++ky){
      int yy = py + ky - 1;
      #pragma unroll
      for (int kx = 0; kx < 3; ++kx){
        int xx = px + kx - 1;
        bool ok = ((unsigned)yy < 256u) && ((unsigned)xx < 512u);
        in[ci][ky*3+kx] = ok ? xc[yy*512 + xx] : 0.f;
      }
    }
  }
  unsigned short* op = out + (long)id*64;
  #pragma unroll 2
  for (int g = 0; g < 8; ++g){
    unsigned pk[4];
    #pragma unroll
    for (int u = 0; u < 8; ++u){
      int co = g*8 + u;
      float s = bi[co];
      #pragma unroll
      for (int ci = 0; ci < 4; ++ci){
        const float* wc = w + (co*4 + ci)*9;
        #pragma unroll
        for (int k = 0; k < 9; ++k) s += in[ci][k]*wc[k];
      }
      s = gelu_f(s);
      unsigned short h = f2bf(s);
      if (u & 1) pk[u>>1] |= ((unsigned)h << 16);
      else       pk[u>>1]  = (unsigned)h;
    }
    uint4 v = {pk[0], pk[1], pk[2], pk[3]};
    *(uint4*)(op + g*8) = v;
  }
}

// conv2 v3 (pixel_shuffle fused): r1 bf16 channels-last -> r2 fp32 (B,1024,2048)
__global__ __launch_bounds__(256)
void conv2_v3(const unsigned short* __restrict__ r1, const float* __restrict__ w,
              const float* __restrict__ bi, float* __restrict__ out)
{
  __shared__ float cbuf[108*68];
  int X0 = blockIdx.x*64, Y0 = blockIdx.y*16, bb = blockIdx.z;
  int cx0 = (X0 >> 2) - 1, cy0 = (Y0 >> 2) - 1;
  int t = threadIdx.x;
  const unsigned short* rb = r1 + (long)bb*256*512*64;
  for (int i4 = t; i4 < 1728; i4 += 256){
    int cell = i4 >> 4, ch4 = (i4 & 15) << 2;
    int cy = cy0 + cell/18, cx = cx0 + cell%18;
    float4 v = {0.f, 0.f, 0.f, 0.f};
    if ((unsigned)cy < 256u && (unsigned)cx < 512u){
      uint2 u = *(const uint2*)&rb[(((long)cy*512 + cx) << 6) + ch4];
      v.x = bf2f((unsigned short)(u.x & 0xffff));
      v.y = bf2f((unsigned short)(u.x >> 16));
      v.z = bf2f((unsigned short)(u.y & 0xffff));
      v.w = bf2f((unsigned short)(u.y >> 16));
    }
    *(float4*)&cbuf[cell*68 + ch4] = v;
  }
  float wv[36];
  #pragma unroll
  for (int k = 0; k < 36; ++k) wv[k] = w[k];
  float bias = bi[0];
  __syncthreads();
  int lx = t & 63, tq = t >> 6;
  int X = X0 + lx;
  #pragma unroll
  for (int j = 0; j < 4; ++j){
    int Y = Y0 + tq*4 + j;
    float s = bias;
    #pragma unroll
    for (int ky = 0; ky < 3; ++ky){
      int yy = Y + ky - 1;
      if ((unsigned)yy >= 1024u) continue;
      int ly = (yy >> 2) - cy0, phy = (yy & 3) << 2;
      #pragma unroll
      for (int kx = 0; kx < 3; ++kx){
        int xx = X + kx - 1;
        if ((unsigned)xx >= 2048u) continue;
        int lxc = (xx >> 2) - cx0;
        const float* cp = &cbuf[(ly*18 + lxc)*68 + phy + (xx & 3)];
        s += cp[0]*wv[ky*3+kx] + cp[16]*wv[9+ky*3+kx]
           + cp[32]*wv[18+ky*3+kx] + cp[48]*wv[27+ky*3+kx];
      }
    }
    out[(((long)bb*1024 + Y) << 11) + X] = s;
  }
}

// fused: unpatchify + residual + final 3x3 conv -> d_out
__global__ __launch_bounds__(256)
void cout_fused(const float* __restrict__ pred, const float* __restrict__ r2,
                const float* __restrict__ w, const float* __restrict__ bi,
                float* __restrict__ out)
{
  __shared__ float tb[18*66];
  int X0 = blockIdx.x*64, Y0 = blockIdx.y*16, bb = blockIdx.z;
  int t = threadIdx.x;
  for (int i = t; i < 1188; i += 256){
    int ly = i/66, lx = i%66;
    int Y = Y0 + ly - 1, X = X0 + lx - 1;
    float v = 0.f;
    if ((unsigned)Y < 1024u && (unsigned)X < 2048u){
      int i2 = Y >> 4, p = Y & 15, j2 = X >> 4, q = X & 15;
      int l = i2*8 + (j2 >> 4);
      int e = ((j2 & 15) << 8) + (p << 4) + q;
      v = pred[(((long)bb*512 + l) << 12) + e] + r2[(((long)bb*1024 + Y) << 11) + X];
    }
    tb[i] = v;
  }
  float w0=w[0], w1=w[1], w2=w[2], w3=w[3], w4=w[4], w5=w[5], w6=w[6], w7=w[7], w8=w[8];
  float bias = bi[0];
  __syncthreads();
  int lx = t & 63, tq = t >> 6;
  #pragma unroll
  for (int j = 0; j < 4; ++j){
    int ry = tq*4 + j;
    const float* c = &tb[ry*66 + lx];
    float s = bias + c[0]*w0 + c[1]*w1 + c[2]*w2
            + c[66]*w3 + c[67]*w4 + c[68]*w5
            + c[132]*w6 + c[133]*w7 + c[134]*w8;
    out[(((long)bb*1024 + Y0 + ry) << 11) + X0 + lx] = s;
  }
}

// ---------------------------------------------------------------------------------------
static inline void gemm_go(hipStream_t st, int TM, const unsigned short* A,
                           const unsigned short* Wt,
                           const float* bias, const float* res, float* Cf, unsigned short* Cb,
                           float* Cp, int splits,
                           int M, int N, int K, int batches,
                           long sA, long sW, long sBias, long sRes, long sC,
                           int wmod, int act)
{
  dim3 g(N/128, M/TM, batches*splits);
  long MN = (long)M*N;
  if (TM == 128)
    gemm_bt<128><<<g, 256, 0, st>>>(A, Wt, bias, res, Cf, Cb, Cp, MN, splits,
                                    M, N, K, N, sA, sW, sBias, sRes, sC, wmod, act);
  else
    gemm_bt<64><<<g, 256, 0, st>>>(A, Wt, bias, res, Cf, Cb, Cp, MN, splits,
                                   M, N, K, N, sA, sW, sBias, sRes, sC, wmod, act);
}

static inline void reduce_go(hipStream_t st, const float* Cp, int splits, int nbat,
                             long MN, int N, const float* bias, const float* res, long sRes,
                             float* Cf, unsigned short* Cb, long sC, int act)
{
  long total4 = (long)nbat*MN/4;
  reduce_ep<<<(int)((total4 + 255)/256), 256, 0, st>>>(Cp, splits, nbat, MN, N,
                                                       bias, res, sRes, Cf, Cb, sC, act);
}

static inline void wmulti_go(hipStream_t st, int njobs,
                             const float* W0, unsigned short* T0, int K0, int N0, int nb0,
                             const float* W1, unsigned short* T1, int K1, int N1, int nb1,
                             const float* W2, unsigned short* T2, int K2, int N2, int nb2,
                             const float* W3, unsigned short* T3, int K3, int N3, int nb3)
{
  WJobs J;
  const float* Ws[4] = {W0, W1, W2, W3};
  unsigned short* Ts[4] = {T0, T1, T2, T3};
  int Ks[4] = {K0, K1, K2, K3}, Ns[4] = {N0, N1, N2, N3}, nbs[4] = {nb0, nb1, nb2, nb3};
  int acc = 0;
  for (int i = 0; i < 4; ++i){
    if (i < njobs){
      J.W[i] = Ws[i]; J.T[i] = Ts[i]; J.K[i] = Ks[i]; J.N[i] = Ns[i];
      J.start[i] = acc;
      acc += nbs[i] * (Ks[i] >> 5) * (Ns[i] >> 5);
    } else {
      J.W[i] = Ws[0]; J.T[i] = Ts[0]; J.K[i] = 32; J.N[i] = 32;
      J.start[i] = 0x7fffffff;
    }
  }
  wtrans_multi<<<acc, 256, 0, st>>>(J);
}

extern "C" void kernel_launch(void* const* d_in, const int* in_sizes, int n_in,
                              void* d_out, int out_size, void* d_ws, size_t ws_size,
                              hipStream_t stream)
{
  const float* x         = (const float*)d_in[0];
  const int*   hard_idx  = (const int*)  d_in[1];
  const float* patch_w   = (const float*)d_in[2];
  const float* patch_b   = (const float*)d_in[3];
  const float* var_embed = (const float*)d_in[4];
  const float* var_query = (const float*)d_in[5];
  const float* agg_wq    = (const float*)d_in[6];
  const float* agg_wk    = (const float*)d_in[7];
  const float* agg_wv    = (const float*)d_in[8];
  const float* agg_wo    = (const float*)d_in[9];
  const float* agg_bo    = (const float*)d_in[10];
  const float* pos_embed = (const float*)d_in[11];
  const float* ln1_w     = (const float*)d_in[12];
  const float* ln1_b     = (const float*)d_in[13];
  const float* qkv_w     = (const float*)d_in[14];
  const float* qkv_b     = (const float*)d_in[15];
  const float* aproj_w   = (const float*)d_in[16];
  const float* aproj_b   = (const float*)d_in[17];
  const float* ln2_w     = (const float*)d_in[18];
  const float* ln2_b     = (const float*)d_in[19];
  const float* fc1_w     = (const float*)d_in[20];
  const float* fc1_b     = (const float*)d_in[21];
  const float* fc2_w     = (const float*)d_in[22];
  const float* fc2_b     = (const float*)d_in[23];
  const float* norm_w    = (const float*)d_in[24];
  const float* norm_b    = (const float*)d_in[25];
  const float* head_w    = (const float*)d_in[26];
  const float* head_b    = (const float*)d_in[27];
  const float* head_out_w= (const float*)d_in[28];
  const float* head_out_b= (const float*)d_in[29];
  const float* p2c1_w    = (const float*)d_in[30];
  const float* p2c1_b    = (const float*)d_in[31];
  const float* p2c2_w    = (const float*)d_in[32];
  const float* p2c2_b    = (const float*)d_in[33];
  const float* cout_w    = (const float*)d_in[34];
  const float* cout_b    = (const float*)d_in[35];

  float* ws = (float*)d_ws;
  float* xt   = ws;                // 1U fp32 stream (B,512,1024)
  float* r2   = ws + 1*UNIT;       // 4U
  float* qkvb = ws + 5*UNIT;       // 3U
  float* pred = ws + 8*UNIT;       // 4U (phase3+)
  unsigned short* rbig = (unsigned short*)(ws + 8*UNIT);  // 16.8M bf16 = 8.4U (phase0)
  float* vb   = ws + 12*UNIT;      // 4U (phase1 early)
  float* Cp   = ws + 12*UNIT;      // 4U split-K partials (after vb dead)
  unsigned short* b16 = (unsigned short*)(ws + 16*UNIT);  // 24M ushorts = 12U
  unsigned short* hn_bf    = b16;                // 1M
  unsigned short* ao_bf    = b16 + 1*UNIT;       // 1M
  unsigned short* ff_bf    = b16 + 2*UNIT;       // 4M
  unsigned short* xp_bf    = b16 + 6*UNIT;       // 1M
  unsigned short* tok_bf   = b16 + 7*UNIT;       // 4M
  unsigned short* aggin_bf = b16 + 11*UNIT;      // 1M
  unsigned short* wt_a     = b16 + 12*UNIT;      // 12M weight arena
  float* tail = ws + 28*UNIT;
  float* pb2  = tail;              // 4096
  float* qv   = tail + 4096;       // 1024
  float* wtl  = tail + 5120;       // 16384
  float* hbuf = tail + 21504;      // 0.25U

  // ---- Phase 0: residual conv path -> r2 ----
  conv1_v3<<<1024, 256, 0, stream>>>(x, p2c1_w, p2c1_b, rbig);
  conv2_v3<<<dim3(32, 64, 2), 256, 0, stream>>>(rbig, p2c2_w, p2c2_b, r2);

  // ---- Phase 1: patch embed + aggregate variables -> xt ----
  unsigned short* wt_patch = wt_a;               // 1M (4 x 256x1024)
  unsigned short* wt_wv    = wt_a + 1*UNIT;      // 1M
  unsigned short* wt_wo    = wt_a + 2*UNIT;      // 1M
  pb2_combine<<<16, 256, 0, stream>>>(patch_b, var_embed, pb2);
  xp_extract<<<1024, 256, 0, stream>>>(x, xp_bf);
  qproj<<<16, 64, 0, stream>>>(var_query, agg_wq, qv);
  wk_fold<<<64, 256, 0, stream>>>(agg_wk, qv, wtl);
  wmulti_go(stream, 3,
            patch_w, wt_patch, 256, 1024, 4,
            agg_wv,  wt_wv,   1024, 1024, 1,
            agg_wo,  wt_wo,   1024, 1024, 1,
            nullptr, nullptr, 0, 0, 0);
  gemm_go(stream, 128, xp_bf, wt_patch, pb2, nullptr, nullptr, tok_bf, nullptr, 1,
          512, 1024, 256, 8, 512L*256, 256L*1024, 1024, 0, 512L*1024, 4, 0);
  gemm_go(stream, 128, tok_bf, wt_wv, nullptr, nullptr, vb, nullptr, nullptr, 1,
          512, 1024, 1024, 8, 512L*1024, 0, 0, 0, 512L*1024, 1, 0);
  agg_attn2<<<dim3(512, 16, 2), 64, 0, stream>>>(tok_bf, vb, wtl, aggin_bf);
  // wo: M=512 x2 batches, split-K 2 -> 256 blocks; reduce adds agg_bo + pos_embed
  gemm_go(stream, 64, aggin_bf, wt_wo, nullptr, nullptr, nullptr, nullptr, Cp, 2,
          512, 1024, 1024, 2, 512L*1024, 0, 0, 0, 512L*1024, 1, 0);
  reduce_go(stream, Cp, 2, 2, 512L*1024, 1024, agg_bo, pos_embed, 0, xt, nullptr,
            512L*1024, 0);

  // ---- Phase 2: transformer blocks ----
  unsigned short* wt_qkv   = wt_a;               // 3M
  unsigned short* wt_aproj = wt_a + 3*UNIT;      // 1M
  unsigned short* wt_fc1   = wt_a + 4*UNIT;      // 4M
  unsigned short* wt_fc2   = wt_a + 8*UNIT;      // 4M

  auto run_block = [&](float* cur, int Nt, int d){
    int rows = 2 * Nt;
    bool dense = (rows >= 1024);
    int TMbig = dense ? 128 : 64;
    long MNq = (long)rows*3072, MNa = (long)rows*1024, MNf = (long)rows*4096;
    wmulti_go(stream, 4,
              qkv_w   + (long)d*1024*3072, wt_qkv,   1024, 3072, 1,
              aproj_w + (long)d*1024*1024, wt_aproj, 1024, 1024, 1,
              fc1_w   + (long)d*1024*4096, wt_fc1,   1024, 4096, 1,
              fc2_w   + (long)d*4096*1024, wt_fc2,   4096, 1024, 1);
    ln_bf<<<rows, 256, 0, stream>>>(cur, ln1_w + d*1024, ln1_b + d*1024, hn_bf);
    gemm_go(stream, TMbig, hn_bf, wt_qkv, qkv_b + d*3072, nullptr, qkvb, nullptr, nullptr, 1,
            rows, 3072, 1024, 1, 0, 0, 0, 0, 0, 1, 0);
    attn_v2<<<dim3(Nt/32, 16, 2), 256, 0, stream>>>(qkvb, ao_bf, Nt);
    // aproj: split-K (dense 4, sparse 8) -> 256 blocks
    {
      int sk = dense ? 4 : 8;
      gemm_go(stream, TMbig, ao_bf, wt_aproj, nullptr, nullptr, nullptr, nullptr, Cp, sk,
              rows, 1024, 1024, 1, 0, 0, 0, 0, 0, 1, 0);
      reduce_go(stream, Cp, sk, 1, MNa, 1024, aproj_b + d*1024, cur, MNa, cur, nullptr, MNa, 0);
    }
    ln_bf<<<rows, 256, 0, stream>>>(cur, ln2_w + d*1024, ln2_b + d*1024, hn_bf);
    if (dense){
      gemm_go(stream, 128, hn_bf, wt_fc1, fc1_b + d*4096, nullptr, nullptr, ff_bf, nullptr, 1,
              rows, 4096, 1024, 1, 0, 0, 0, 0, 0, 1, 1);
    } else {
      gemm_go(stream, 64, hn_bf, wt_fc1, nullptr, nullptr, nullptr, nullptr, Cp, 2,
              rows, 4096, 1024, 1, 0, 0, 0, 0, 0, 1, 1);
      reduce_go(stream, Cp, 2, 1, MNf, 4096, fc1_b + d*4096, nullptr, 0, nullptr, ff_bf, MNf, 1);
    }
    {
      int sk = dense ? 4 : 8;
      gemm_go(stream, TMbig, ff_bf, wt_fc2, nullptr, nullptr, nullptr, nullptr, Cp, sk,
              rows, 1024, 4096, 1, 0, 0, 0, 0, 0, 1, 0);
      reduce_go(stream, Cp, sk, 1, MNa, 1024, fc2_b + d*1024, cur, MNa, cur, nullptr, MNa, 0);
    }
  };

  run_block(xt, 512, 0);
  run_block(xt, 512, 1);
  gather_rows<<<256, 256, 0, stream>>>(xt, hard_idx, hbuf);
  run_block(hbuf, 128, 2);
  run_block(hbuf, 128, 3);
  run_block(hbuf, 128, 4);
  scatter_rows<<<256, 256, 0, stream>>>(hbuf, hard_idx, xt);
  run_block(xt, 512, 5);

  // ---- Phase 3: final LN + head ----
  unsigned short* wt_h1 = wt_a;                  // 1M
  unsigned short* wt_h2 = wt_a + 1*UNIT;         // 1M
  unsigned short* wt_ho = wt_a + 2*UNIT;         // 4M
  wmulti_go(stream, 3,
            head_w,              wt_h1, 1024, 1024, 1,
            head_w + 1024L*1024, wt_h2, 1024, 1024, 1,
            head_out_w,          wt_ho, 1024, 4096, 1,
            nullptr, nullptr, 0, 0, 0);
  ln_bf<<<1024, 256, 0, stream>>>(xt, norm_w, norm_b, hn_bf);
  gemm_go(stream, 64, hn_bf, wt_h1, nullptr, nullptr, nullptr, nullptr, Cp, 2,
          1024, 1024, 1024, 1, 0, 0, 0, 0, 0, 1, 1);
  reduce_go(stream, Cp, 2, 1, 1024L*1024, 1024, head_b, nullptr, 0, nullptr, ao_bf,
            1024L*1024, 1);
  gemm_go(stream, 64, ao_bf, wt_h2, nullptr, nullptr, nullptr, nullptr, Cp, 2,
          1024, 1024, 1024, 1, 0, 0, 0, 0, 0, 1, 1);
  reduce_go(stream, Cp, 2, 1, 1024L*1024, 1024, head_b + 1024, nullptr, 0, nullptr, hn_bf,
            1024L*1024, 1);
  gemm_go(stream, 128, hn_bf, wt_ho, head_out_b, nullptr, pred, nullptr, nullptr, 1,
          1024, 4096, 1024, 1, 0, 0, 0, 0, 0, 1, 0);

  // ---- Phase 4: fused unpatchify + residual + final conv ----
  cout_fused<<<dim3(32, 64, 2), 256, 0, stream>>>(pred, r2, cout_w, cout_b, (float*)d_out);
}